// Round 13
// baseline (218.383 us; speedup 1.0000x reference)
//
#include <hip/hip_runtime.h>
#include <math.h>

#define S_LEN 512
#define HID 2048
#define NH 16
#define NKV 4
#define HD 128
#define CL 8192
#define TAILN (CL - S_LEN)
#define NKO (NKV * S_LEN * HD)
#define KS1 16                 // key partitions pass 1 (128-q blocks)
#define KCH1 (CL / KS1)        // 512
#define KS2 8                  // key partitions pass 2 (128-q blocks)
#define KCH2 (CL / KS2)        // 1024
#define INV_SQRT_HD 0.08838834764831845f

typedef unsigned short u16;
typedef unsigned int u32;
typedef __attribute__((ext_vector_type(8))) unsigned short u16x8;
typedef __attribute__((ext_vector_type(4))) unsigned short u16x4;
typedef __attribute__((ext_vector_type(8))) short bf16x8;
typedef __attribute__((ext_vector_type(4))) float f32x4;

enum {
  SC_AMAX_X = 0, SC_AMAX_CK, SC_AMAX_CK_TAIL, SC_AMAX_CV, SC_AMAX_CV_TAIL,
  SC_AMAX_Q, SC_AMAX_K, SC_AMAX_V, SC_AMAX_AO, SC_MIN_L,
  SC_NUM
};

__device__ __forceinline__ float warpMax64(float v) {
  #pragma unroll
  for (int o = 32; o; o >>= 1) v = fmaxf(v, __shfl_down(v, o, 64));
  return v;
}
__device__ __forceinline__ float warpMin64(float v) {
  #pragma unroll
  for (int o = 32; o; o >>= 1) v = fminf(v, __shfl_down(v, o, 64));
  return v;
}
// requires blockDim.x == 256
__device__ __forceinline__ float blockMax256(float v) {
  __shared__ float sm_[4];
  __syncthreads();
  v = warpMax64(v);
  if ((threadIdx.x & 63) == 0) sm_[threadIdx.x >> 6] = v;
  __syncthreads();
  return fmaxf(fmaxf(sm_[0], sm_[1]), fmaxf(sm_[2], sm_[3]));
}
__device__ __forceinline__ float blockMin256(float v) {
  __shared__ float sn_[4];
  __syncthreads();
  v = warpMin64(v);
  if ((threadIdx.x & 63) == 0) sn_[threadIdx.x >> 6] = v;
  __syncthreads();
  return fminf(fminf(sn_[0], sn_[1]), fminf(sn_[2], sn_[3]));
}
__device__ __forceinline__ void atomicMinPosF(float* a, float v) {
  atomicMin((unsigned int*)a, __float_as_uint(v));
}
__device__ __forceinline__ float clampq(float q) {
  return fminf(fmaxf(q, -128.f), 127.f);
}
__device__ __forceinline__ u16 bf16bits(float f) {
  return (u16)(__float_as_uint(f) >> 16);   // exact for small integers
}
__device__ __forceinline__ float mk_scale(float am) {
  return fmaxf(am, 1e-8f) / 127.f;
}
__device__ __forceinline__ void gl2lds16(const u16* g, u16* l) {
  __builtin_amdgcn_global_load_lds((const __attribute__((address_space(1))) void*)g,
                                   (__attribute__((address_space(3))) void*)l, 16, 0, 0);
}

// fused pre-pass absmax: blocks [0,512) hidden, [512,1024) cache_k, [1024,1536) cache_v
__global__ __launch_bounds__(256) void k_pre(const float* __restrict__ hidden,
                                             const float* __restrict__ ck, const float* __restrict__ cv,
                                             float* __restrict__ pp) {
  int b = blockIdx.x, tid = threadIdx.x;
  if (b < 512) {
    const int n4 = S_LEN * HID / 4;
    float m = 0.f;
    const float4* x4 = (const float4*)hidden;
    for (int i = b * 256 + tid; i < n4; i += 512 * 256) {
      float4 v = x4[i];
      m = fmaxf(m, fmaxf(fmaxf(fabsf(v.x), fabsf(v.y)), fmaxf(fabsf(v.z), fabsf(v.w))));
    }
    m = blockMax256(m);
    if (tid == 0) pp[b] = m;
  } else {
    int isv = b >= 1024;
    int bb = b - (isv ? 1024 : 512);
    const float4* x4 = (const float4*)(isv ? cv : ck);
    const int n4 = NKV * CL * HD / 4;
    float mf = 0.f, mt = 0.f;
    for (int i = bb * 256 + tid; i < n4; i += 512 * 256) {
      float4 v = x4[i];
      float a = fmaxf(fmaxf(fabsf(v.x), fabsf(v.y)), fmaxf(fabsf(v.z), fabsf(v.w)));
      mf = fmaxf(mf, a);
      int t = (i >> 5) & (CL - 1);
      if (t >= S_LEN) mt = fmaxf(mt, a);
    }
    mf = blockMax256(mf);
    mt = blockMax256(mt);
    if (tid == 0) {
      pp[512 + isv * 1024 + bb] = mf;
      pp[1024 + isv * 1024 + bb] = mt;
    }
  }
}

// single block: fold 5 ranges of 512 partials into SC slots; also init SC_MIN_L
__global__ __launch_bounds__(256) void k_reduce_pre(const float* __restrict__ pp, float* __restrict__ sc) {
  const int slots[5] = {SC_AMAX_X, SC_AMAX_CK, SC_AMAX_CK_TAIL, SC_AMAX_CV, SC_AMAX_CV_TAIL};
  if (threadIdx.x == 0) sc[SC_MIN_L] = INFINITY;
  #pragma unroll
  for (int r = 0; r < 5; r++) {
    float v = fmaxf(pp[r * 512 + threadIdx.x], pp[r * 512 + 256 + threadIdx.x]);
    v = blockMax256(v);
    if (threadIdx.x == 0) sc[slots[r]] = v;
  }
}

// all 4 weight matrices, one block per output row; single pass (row cached in registers)
__global__ __launch_bounds__(256) void k_quant_w_all(const float* __restrict__ Wq, const float* __restrict__ Wk,
                                                     const float* __restrict__ Wv, const float* __restrict__ Wo,
                                                     u16* __restrict__ WQb, u16* __restrict__ WKb,
                                                     u16* __restrict__ WVb, u16* __restrict__ WOb,
                                                     float* __restrict__ SWq, float* __restrict__ SWk,
                                                     float* __restrict__ SWv, float* __restrict__ SWo) {
  int r = blockIdx.x;
  const float* W; u16* Wb; float* SW; int row;
  if (r < 2048)      { W = Wq; Wb = WQb; SW = SWq; row = r; }
  else if (r < 2560) { W = Wk; Wb = WKb; SW = SWk; row = r - 2048; }
  else if (r < 3072) { W = Wv; Wb = WVb; SW = SWv; row = r - 2560; }
  else               { W = Wo; Wb = WOb; SW = SWo; row = r - 3072; }
  size_t base = (size_t)row * HID;
  const float4* w4 = (const float4*)(W + base);
  int tid = threadIdx.x;
  float4 va = w4[tid];
  float4 vb = w4[tid + 256];
  float am = fmaxf(fmaxf(fmaxf(fabsf(va.x), fabsf(va.y)), fmaxf(fabsf(va.z), fabsf(va.w))),
                   fmaxf(fmaxf(fabsf(vb.x), fabsf(vb.y)), fmaxf(fabsf(vb.z), fabsf(vb.w))));
  am = blockMax256(am);
  float s = fmaxf(am, 1e-8f) / 127.f;
  if (tid == 0) SW[row] = s;
  u16x4 oa, ob;
  oa[0] = bf16bits(clampq(rintf(va.x / s)));
  oa[1] = bf16bits(clampq(rintf(va.y / s)));
  oa[2] = bf16bits(clampq(rintf(va.z / s)));
  oa[3] = bf16bits(clampq(rintf(va.w / s)));
  ob[0] = bf16bits(clampq(rintf(vb.x / s)));
  ob[1] = bf16bits(clampq(rintf(vb.y / s)));
  ob[2] = bf16bits(clampq(rintf(vb.z / s)));
  ob[3] = bf16bits(clampq(rintf(vb.w / s)));
  *(u16x4*)(Wb + base + (size_t)tid * 4) = oa;
  *(u16x4*)(Wb + base + (size_t)(tid + 256) * 4) = ob;
}

// activation fake-quant -> bf16 integer codes; scale computed inline from amax slot
__global__ __launch_bounds__(256) void k_quant_act_b(const float* __restrict__ in, u16* __restrict__ outp,
                                                     int n4, const float* __restrict__ sc, int axslot) {
  float s = mk_scale(sc[axslot]);
  const float4* i4 = (const float4*)in;
  for (int i = blockIdx.x * 256 + threadIdx.x; i < n4; i += gridDim.x * 256) {
    float4 v = i4[i];
    u16x4 o;
    o[0] = bf16bits(clampq(rintf(v.x / s)));
    o[1] = bf16bits(clampq(rintf(v.y / s)));
    o[2] = bf16bits(clampq(rintf(v.z / s)));
    o[3] = bf16bits(clampq(rintf(v.w / s)));
    *(u16x4*)(outp + (size_t)i * 4) = o;
  }
}

// QB f32 [S][NH*HD] -> QI bf16-int [NH][S][HD]
__global__ __launch_bounds__(256) void k_quant_q(const float* __restrict__ QB, u16* __restrict__ QI,
                                                 const float* __restrict__ sc) {
  int idx = blockIdx.x * 256 + threadIdx.x;
  float s = mk_scale(sc[SC_AMAX_Q]);
  int e = idx * 4;
  int srow = e >> 11, rem = e & 2047;
  int h = rem >> 7, d = rem & 127;
  float4 v = *(const float4*)&QB[e];
  u16x4 o;
  o[0] = bf16bits(clampq(rintf(v.x / s)));
  o[1] = bf16bits(clampq(rintf(v.y / s)));
  o[2] = bf16bits(clampq(rintf(v.z / s)));
  o[3] = bf16bits(clampq(rintf(v.w / s)));
  *(u16x4*)(QI + ((size_t)h * S_LEN + srow) * HD + d) = o;
}

#define GQ_STAGE(BUF, K0)                                                          \
  {                                                                                \
    _Pragma("unroll")                                                              \
    for (int i = 0; i < 2; i++) {                                                  \
      int b = tid + i * 256;                                                       \
      int row = b >> 3, c8d = b & 7, c8s = c8d ^ (row & 7);                        \
      gl2lds16(A + (size_t)(r0 + row) * HID + (K0) + c8s * 8, Al[BUF] + b * 8);    \
    }                                                                              \
    _Pragma("unroll")                                                              \
    for (int i = 0; i < 2; i++) {                                                  \
      int b = tid + i * 256;                                                       \
      int row = b >> 3, c8d = b & 7, c8s = c8d ^ (row & 7);                        \
      gl2lds16(B + (size_t)(c0 + row) * HID + (K0) + c8s * 8, Bl[BUF] + b * 8);    \
    }                                                                              \
  }

#define GQ_TILE(BUF)                                                               \
  {                                                                                \
    _Pragma("unroll")                                                              \
    for (int ks = 0; ks < 2; ks++) {                                               \
      bf16x8 af[2], bfr[2];                                                        \
      _Pragma("unroll")                                                            \
      for (int a = 0; a < 2; a++) {                                                \
        int row = wy * 32 + a * 16 + c;                                            \
        af[a] = *(const bf16x8*)(Al[BUF] + row * 64 + (((4 * ks + g) ^ (row & 7)) * 8)); \
      }                                                                            \
      _Pragma("unroll")                                                            \
      for (int b2 = 0; b2 < 2; b2++) {                                             \
        int row = wx * 32 + b2 * 16 + c;                                           \
        bfr[b2] = *(const bf16x8*)(Bl[BUF] + row * 64 + (((4 * ks + g) ^ (row & 7)) * 8)); \
      }                                                                            \
      _Pragma("unroll")                                                            \
      for (int a = 0; a < 2; a++)                                                  \
        _Pragma("unroll")                                                          \
        for (int b2 = 0; b2 < 2; b2++)                                             \
          acc[a][b2] = __builtin_amdgcn_mfma_f32_16x16x32_bf16(af[a], bfr[b2], acc[a][b2], 0, 0, 0); \
    }                                                                              \
  }

// fused QKV GEMM: C = (XI x W^T) * (sx*SW[col]) + bias; 64x64 tiles, dbuf, grid (48, 8)
__global__ __launch_bounds__(256) void k_gemm_qkv(const u16* __restrict__ A,
                                                  const u16* __restrict__ WQb, const u16* __restrict__ WKb,
                                                  const u16* __restrict__ WVb,
                                                  const float* __restrict__ SWq, const float* __restrict__ SWk,
                                                  const float* __restrict__ SWv,
                                                  const float* __restrict__ bq, const float* __restrict__ bk,
                                                  const float* __restrict__ bv,
                                                  const float* __restrict__ sc,
                                                  float* __restrict__ QB, float* __restrict__ KB,
                                                  float* __restrict__ VB) {
  __shared__ u16 Al[2][64 * 64];
  __shared__ u16 Bl[2][64 * 64];
  int bx = blockIdx.x;
  const u16* B; const float* SW; const float* bias; float* C; int N, c0;
  if (bx < 32)      { B = WQb; SW = SWq; bias = bq; C = QB; N = HID; c0 = bx * 64; }
  else if (bx < 40) { B = WKb; SW = SWk; bias = bk; C = KB; N = NKV * HD; c0 = (bx - 32) * 64; }
  else              { B = WVb; SW = SWv; bias = bv; C = VB; N = NKV * HD; c0 = (bx - 40) * 64; }
  int tid = threadIdx.x, lane = tid & 63, w = tid >> 6;
  int g = lane >> 4, c = lane & 15;
  int wy = w >> 1, wx = w & 1;
  int r0 = blockIdx.y * 64;
  float sx = mk_scale(sc[SC_AMAX_X]);
  f32x4 acc[2][2] = {};
  GQ_STAGE(0, 0)
  __syncthreads();
  for (int k0 = 0; k0 < HID; k0 += 128) {
    GQ_STAGE(1, k0 + 64)
    GQ_TILE(0)
    __syncthreads();
    if (k0 + 128 < HID) GQ_STAGE(0, k0 + 128)
    GQ_TILE(1)
    __syncthreads();
  }
  #pragma unroll
  for (int a = 0; a < 2; a++)
    #pragma unroll
    for (int b2 = 0; b2 < 2; b2++) {
      int col = c0 + wx * 32 + b2 * 16 + c;
      float sca = sx * SW[col];
      float bs = bias[col];
      #pragma unroll
      for (int r = 0; r < 4; r++) {
        int row = r0 + wy * 32 + a * 16 + 4 * g + r;
        C[(size_t)row * N + col] = acc[a][b2][r] * sca + bs;
      }
    }
}

// O-projection GEMM (M=S, N=K=HID), dbuf
__global__ __launch_bounds__(256) void k_gemm_q(const u16* __restrict__ A, const u16* __restrict__ B,
                                                const float* __restrict__ SW, const float* __restrict__ sc,
                                                int axslot, float* __restrict__ C, int M, int N, int K) {
  __shared__ u16 Al[2][64 * 64];
  __shared__ u16 Bl[2][64 * 64];
  int tid = threadIdx.x, lane = tid & 63, w = tid >> 6;
  int g = lane >> 4, c = lane & 15;
  int wy = w >> 1, wx = w & 1;
  int r0 = blockIdx.y * 64, c0 = blockIdx.x * 64;
  float sx = mk_scale(sc[axslot]);
  f32x4 acc[2][2] = {};
  GQ_STAGE(0, 0)
  __syncthreads();
  for (int k0 = 0; k0 < HID; k0 += 128) {
    GQ_STAGE(1, k0 + 64)
    GQ_TILE(0)
    __syncthreads();
    if (k0 + 128 < HID) GQ_STAGE(0, k0 + 128)
    GQ_TILE(1)
    __syncthreads();
  }
  #pragma unroll
  for (int a = 0; a < 2; a++)
    #pragma unroll
    for (int b2 = 0; b2 < 2; b2++) {
      int col = c0 + wx * 32 + b2 * 16 + c;
      float sca = sx * SW[col];
      #pragma unroll
      for (int r = 0; r < 4; r++) {
        int row = r0 + wy * 32 + a * 16 + 4 * g + r;
        C[(size_t)row * N + col] = acc[a][b2][r] * sca;
      }
    }
}

// fused: RoPE(Q), RoPE(K), absmax(V) -> per-block partials PR[bid]. grid = 2816
__global__ __launch_bounds__(256) void k_rope_amax(float* __restrict__ QB, float* __restrict__ KB,
                                                   const float* __restrict__ VB,
                                                   const float* __restrict__ cosb, const float* __restrict__ sinb,
                                                   float* __restrict__ PR) {
  const int nQ = S_LEN * NH * 64;     // 524288
  const int nK = S_LEN * NKV * 64;    // 131072
  int idx = blockIdx.x * 256 + threadIdx.x;
  float am = 0.f;
  if (idx < nQ) {
    int s = idx >> 10, rem = idx & 1023, h = rem >> 6, d = rem & 63;
    float c1 = cosb[s * HD + d], s1 = sinb[s * HD + d];
    float c2 = cosb[s * HD + d + 64], s2 = sinb[s * HD + d + 64];
    float* p = &QB[(size_t)s * (NH * HD) + h * HD + d];
    float x1 = p[0], x2 = p[64];
    float y1 = x1 * c1 - x2 * s1;
    float y2 = x2 * c2 + x1 * s2;
    p[0] = y1; p[64] = y2;
    am = fmaxf(fabsf(y1), fabsf(y2));
  } else if (idx < nQ + nK) {
    int j = idx - nQ;
    int s = j >> 8, rem = j & 255, h = rem >> 6, d = rem & 63;
    float c1 = cosb[s * HD + d], s1 = sinb[s * HD + d];
    float c2 = cosb[s * HD + d + 64], s2 = sinb[s * HD + d + 64];
    float* p = &KB[(size_t)s * (NKV * HD) + h * HD + d];
    float x1 = p[0], x2 = p[64];
    float y1 = x1 * c1 - x2 * s1;
    float y2 = x2 * c2 + x1 * s2;
    p[0] = y1; p[64] = y2;
    am = fmaxf(fabsf(y1), fabsf(y2));
  } else {
    int j = idx - nQ - nK;
    float4 v = ((const float4*)VB)[j];
    am = fmaxf(fmaxf(fabsf(v.x), fabsf(v.y)), fmaxf(fabsf(v.z), fabsf(v.w)));
  }
  am = blockMax256(am);
  if (threadIdx.x == 0) PR[blockIdx.x] = am;
}

// single block: fold rope partials into SC_AMAX_{Q,K,V}
__global__ __launch_bounds__(256) void k_reduce_rope(const float* __restrict__ PR, float* __restrict__ sc) {
  float v = 0.f;
  #pragma unroll
  for (int i = 0; i < 8; i++) v = fmaxf(v, PR[threadIdx.x + 256 * i]);
  v = blockMax256(v);
  if (threadIdx.x == 0) sc[SC_AMAX_Q] = v;
  v = fmaxf(PR[2048 + threadIdx.x], PR[2048 + 256 + threadIdx.x]);
  v = blockMax256(v);
  if (threadIdx.x == 0) sc[SC_AMAX_K] = v;
  v = PR[2560 + threadIdx.x];
  v = blockMax256(v);
  if (threadIdx.x == 0) sc[SC_AMAX_V] = v;
}

// fused cache rebuild + V transpose + kvout. grid = NKV*128*2 (K tiles then V tiles)
__global__ __launch_bounds__(256) void k_build_cache2(const float* __restrict__ ck, const float* __restrict__ cv,
                                                      const float* __restrict__ KB, const float* __restrict__ VB,
                                                      u16* __restrict__ KCb, u16* __restrict__ VCb,
                                                      u16* __restrict__ VT, float* __restrict__ dout,
                                                      const float* __restrict__ sc) {
  __shared__ u16 T[64][140];
  int b = blockIdx.x;
  int isv = b >= NKV * 128;
  int bb = b - isv * NKV * 128;
  int kvh = bb >> 7, tb = bb & 127;
  float s1 = mk_scale(sc[isv ? SC_AMAX_CV : SC_AMAX_CK]);
  float tq = fminf(rintf(sc[isv ? SC_AMAX_CV_TAIL : SC_AMAX_CK_TAIL] / s1), 127.f) * s1;
  float s2 = fmaxf(fmaxf(tq, sc[isv ? SC_AMAX_V : SC_AMAX_K]), 1e-8f) / 127.f;
  float so = mk_scale(sc[isv ? SC_AMAX_V : SC_AMAX_K]);
  const float* cache = isv ? cv : ck;
  const float* fresh = isv ? VB : KB;
  u16* Cb = isv ? VCb : KCb;
  int tid = threadIdx.x;
  int t0 = tb * 64;
  #pragma unroll
  for (int i = 0; i < 8; i++) {
    int idx = tid + i * 256;
    int t = idx >> 5, d4 = (idx & 31) << 2;
    int tt = t0 + t;
    float4 x;
    float q0_, q1_, q2_, q3_;
    if (tt < TAILN) {
      x = *(const float4*)&cache[((size_t)kvh * CL + tt + S_LEN) * HD + d4];
      q0_ = clampq(rintf(clampq(rintf(x.x / s1)) * s1 / s2));
      q1_ = clampq(rintf(clampq(rintf(x.y / s1)) * s1 / s2));
      q2_ = clampq(rintf(clampq(rintf(x.z / s1)) * s1 / s2));
      q3_ = clampq(rintf(clampq(rintf(x.w / s1)) * s1 / s2));
    } else {
      x = *(const float4*)&fresh[(size_t)(tt - TAILN) * (NKV * HD) + kvh * HD + d4];
      q0_ = clampq(rintf(x.x / s2));
      q1_ = clampq(rintf(x.y / s2));
      q2_ = clampq(rintf(x.z / s2));
      q3_ = clampq(rintf(x.w / s2));
      float4 o;
      o.x = clampq(rintf(x.x / so)) * so;
      o.y = clampq(rintf(x.y / so)) * so;
      o.z = clampq(rintf(x.z / so)) * so;
      o.w = clampq(rintf(x.w / so)) * so;
      *(float4*)&dout[(size_t)S_LEN * HID + (size_t)isv * NKO +
                      ((size_t)kvh * S_LEN + (tt - TAILN)) * HD + d4] = o;
    }
    u16x4 ov;
    ov[0] = bf16bits(q0_); ov[1] = bf16bits(q1_); ov[2] = bf16bits(q2_); ov[3] = bf16bits(q3_);
    *(u16x4*)(Cb + ((size_t)kvh * CL + tt) * HD + d4) = ov;
    if (isv) *(u16x4*)&T[t][d4] = ov;
  }
  if (isv) {
    __syncthreads();
    #pragma unroll
    for (int i = 0; i < 4; i++) {
      int j = tid + i * 256;          // 0..1023
      int d = j >> 3, tc = (j & 7) << 3;
      u16x8 v;
      #pragma unroll
      for (int k = 0; k < 8; k++) v[k] = T[tc + k][d];
      *(u16x8*)(VT + ((size_t)kvh * HD + d) * CL + t0 + tc) = v;
    }
  }
}

#define M1_STAGE(BUF, KBASE)                                                       \
  {                                                                                \
    const u16* kgt = Kg + (size_t)(KBASE) * HD;                                    \
    _Pragma("unroll")                                                              \
    for (int i = 0; i < 4; i++) {                                                  \
      int b = tid + i * 256;                                                       \
      int row = b >> 4, c8d = b & 15, c8s = c8d ^ (row & 7);                       \
      gl2lds16(kgt + row * HD + c8s * 8, Kl[BUF] + b * 8);                         \
    }                                                                              \
  }

// swapped QK^T (identical MFMA pattern to pass 2 => identical integer scores);
// per-lane row stats with batched per-kf update
#define M1_TILE(BUF, KBASE)                                                        \
  {                                                                                \
    const int kbase_ = (KBASE);                                                    \
    _Pragma("unroll")                                                              \
    for (int kf = 0; kf < 4; kf++) {                                               \
      f32x4 s40 = {0.f, 0.f, 0.f, 0.f}, s41 = {0.f, 0.f, 0.f, 0.f};                \
      int krow = kf * 16 + c;                                                      \
      _Pragma("unroll")                                                            \
      for (int ds = 0; ds < 4; ds++) {                                             \
        bf16x8 kf8 = *(const bf16x8*)(Kl[BUF] + krow * HD + (((4 * ds + g) ^ (krow & 7)) * 8)); \
        s40 = __builtin_amdgcn_mfma_f32_16x16x32_bf16(kf8, qf[0][ds], s40, 0, 0, 0); \
        s41 = __builtin_amdgcn_mfma_f32_16x16x32_bf16(kf8, qf[1][ds], s41, 0, 0, 0); \
      }                                                                            \
      int keyb = kbase_ + kf * 16 + 4 * g;                                         \
      float4 mv0 = *(const float4*)&mrb0[keyb];                                    \
      float v0 = fmaf(s40[0], sscale, mv0.x);                                      \
      float v1 = fmaf(s40[1], sscale, mv0.y);                                      \
      float v2 = fmaf(s40[2], sscale, mv0.z);                                      \
      float v3 = fmaf(s40[3], sscale, mv0.w);                                      \
      float tmax = fmaxf(fmaxf(v0, v1), fmaxf(v2, v3));                            \
      float nm = fmaxf(m[0], tmax);                                                \
      float e0 = __expf(v0 - nm), e1 = __expf(v1 - nm);                            \
      float e2 = __expf(v2 - nm), e3 = __expf(v3 - nm);                            \
      l[0] = fmaf(l[0], __expf(m[0] - nm), (e0 + e1) + (e2 + e3));                 \
      m[0] = nm;                                                                   \
      float4 mv1 = *(const float4*)&mrb1[keyb];                                    \
      v0 = fmaf(s41[0], sscale, mv1.x);                                            \
      v1 = fmaf(s41[1], sscale, mv1.y);                                            \
      v2 = fmaf(s41[2], sscale, mv1.z);                                            \
      v3 = fmaf(s41[3], sscale, mv1.w);                                            \
      tmax = fmaxf(fmaxf(v0, v1), fmaxf(v2, v3));                                  \
      nm = fmaxf(m[1], tmax);                                                      \
      e0 = __expf(v0 - nm); e1 = __expf(v1 - nm);                                  \
      e2 = __expf(v2 - nm); e3 = __expf(v3 - nm);                                  \
      l[1] = fmaf(l[1], __expf(m[1] - nm), (e0 + e1) + (e2 + e3));                 \
      m[1] = nm;                                                                   \
    }                                                                              \
  }

// pass 1: 4 waves x 32 q (128 q/block); swapped MFMA QK^T, dbuf unroll-2.
// grid = NH*4*KS1 = 1024, 256 thr, XCD-chunked
__global__ __launch_bounds__(256) void k_mattn1(const u16* __restrict__ QI, const u16* __restrict__ KCb,
                                                const float* __restrict__ mask, const float* __restrict__ sc,
                                                float* __restrict__ PM, float* __restrict__ PL) {
  __shared__ u16 Kl[2][64 * HD];   // 32 KB
  int bid = blockIdx.x;
  int wki = (bid & 7) * (NH * 4 * KS1 / 8) + (bid >> 3);
  int kc = wki >> 6, rem2 = wki & 63, qb = rem2 >> 4, h = rem2 & 15, kv = h >> 2;
  int tid = threadIdx.x, lane = tid & 63, wv = tid >> 6, g = lane >> 4, c = lane & 15;
  float sq  = mk_scale(sc[SC_AMAX_Q]);
  float sck = mk_scale(sc[SC_AMAX_CK]);
  float tqk = fminf(rintf(sc[SC_AMAX_CK_TAIL] / sck), 127.f) * sck;
  float skn = fmaxf(fmaxf(tqk, sc[SC_AMAX_K]), 1e-8f) / 127.f;
  float sscale = sq * skn * INV_SQRT_HD;
  int q0 = qb * 128 + wv * 32;
  bf16x8 qf[2][4];
  #pragma unroll
  for (int u = 0; u < 2; u++) {
    const u16* qrow = QI + ((size_t)h * S_LEN + q0 + 16 * u + c) * HD + g * 8;
    #pragma unroll
    for (int ds = 0; ds < 4; ds++) qf[u][ds] = *(const bf16x8*)(qrow + 32 * ds);
  }
  float m[2] = {-INFINITY, -INFINITY}, l[2] = {0.f, 0.f};
  const float* mrb0 = mask + (size_t)(q0 + c) * CL;
  const float* mrb1 = mask + (size_t)(q0 + 16 + c) * CL;
  int kbase0 = kc * KCH1;
  const u16* Kg = KCb + (size_t)kv * CL * HD;
  M1_STAGE(0, kbase0)
  __syncthreads();
  for (int kb = 0; kb < KCH1; kb += 128) {
    M1_STAGE(1, kbase0 + kb + 64)
    M1_TILE(0, kbase0 + kb)
    __syncthreads();
    if (kb + 128 < KCH1) M1_STAGE(0, kbase0 + kb + 128)
    M1_TILE(1, kbase0 + kb + 64)
    __syncthreads();
  }
  // reduce across the 4 g-groups (disjoint key subsets of the same q row)
  #pragma unroll
  for (int u = 0; u < 2; u++) {
    #pragma unroll
    for (int off = 16; off < 64; off <<= 1) {
      float om = __shfl_xor(m[u], off, 64);
      float ol = __shfl_xor(l[u], off, 64);
      float nm = fmaxf(m[u], om);
      l[u] = l[u] * __expf(m[u] - nm) + ol * __expf(om - nm);
      m[u] = nm;
    }
  }
  if (g == 0) {
    size_t base = ((size_t)kc * NH + h) * S_LEN + q0;
    PM[base + c] = m[0]; PL[base + c] = l[0];
    PM[base + 16 + c] = m[1]; PL[base + 16 + c] = l[1];
  }
}

__global__ __launch_bounds__(256) void k_merge4(const float* __restrict__ PM, const float* __restrict__ PL,
                                                float* __restrict__ MLm, float* __restrict__ MLl, float* sc) {
  int idx = blockIdx.x * 256 + threadIdx.x;   // NH*S_LEN = 8192
  const int st = NH * S_LEN;
  float m = PM[idx];
  #pragma unroll
  for (int p = 1; p < KS1; p++) m = fmaxf(m, PM[p * st + idx]);
  float l = 0.f;
  #pragma unroll
  for (int p = 0; p < KS1; p++) l += PL[p * st + idx] * __expf(PM[p * st + idx] - m);
  MLm[idx] = m; MLl[idx] = l;
  float lm = blockMin256(l);
  if (threadIdx.x == 0) atomicMinPosF(&sc[SC_MIN_L], lm);
}

#define M2_STAGE(BUF, KBASE)                                                       \
  {                                                                                \
    const u16* kgt = Kg + (size_t)(KBASE) * HD;                                    \
    const u16* vgt = Vg + (KBASE);                                                 \
    _Pragma("unroll")                                                              \
    for (int i = 0; i < 4; i++) {                                                  \
      int b = tid + i * 256;                                                       \
      int row = b >> 4, c8d = b & 15, c8s = c8d ^ (row & 7);                       \
      gl2lds16(kgt + row * HD + c8s * 8, Kl[BUF] + b * 8);                         \
    }                                                                              \
    _Pragma("unroll")                                                              \
    for (int i = 0; i < 4; i++) {                                                  \
      int b = tid + i * 256;                                                       \
      int row = b >> 3, c8d = b & 7, c8s = c8d ^ (row & 7);                        \
      gl2lds16(vgt + (size_t)row * CL + c8s * 8, Vl[BUF] + b * 8);                 \
    }                                                                              \
  }

// swapped QK^T (integer-exact => bit-identical scores); P assembled in-register via shfl
#define M2_TILE(BUF, KBASE)                                                        \
  {                                                                                \
    const int kbase_ = (KBASE);                                                    \
    u32 pw[2][2][4];  /* [u][word][kf], all compile-time indexed */                \
    _Pragma("unroll")                                                              \
    for (int kf = 0; kf < 4; kf++) {                                               \
      f32x4 s40 = {0.f, 0.f, 0.f, 0.f}, s41 = {0.f, 0.f, 0.f, 0.f};                \
      int krow = kf * 16 + c;                                                      \
      _Pragma("unroll")                                                            \
      for (int ds = 0; ds < 4; ds++) {                                             \
        bf16x8 kf8 = *(const bf16x8*)(Kl[BUF] + krow * HD + (((4 * ds + g) ^ (krow & 7)) * 8)); \
        s40 = __builtin_amdgcn_mfma_f32_16x16x32_bf16(kf8, qf[0][ds], s40, 0, 0, 0); \
        s41 = __builtin_amdgcn_mfma_f32_16x16x32_bf16(kf8, qf[1][ds], s41, 0, 0, 0); \
      }                                                                            \
      int keyb = kbase_ + kf * 16 + 4 * g;                                         \
      float4 mv0 = *(const float4*)&mrb0[keyb];                                    \
      float p0 = fminf(rintf(__expf(fmaf(s40[0], sscale, mv0.x) - mreg[0]) * cvl[0]), 127.f); \
      float p1 = fminf(rintf(__expf(fmaf(s40[1], sscale, mv0.y) - mreg[0]) * cvl[0]), 127.f); \
      float p2 = fminf(rintf(__expf(fmaf(s40[2], sscale, mv0.z) - mreg[0]) * cvl[0]), 127.f); \
      float p3 = fminf(rintf(__expf(fmaf(s40[3], sscale, mv0.w) - mreg[0]) * cvl[0]), 127.f); \
      pw[0][0][kf] = (u32)bf16bits(p0) | ((u32)bf16bits(p1) << 16);                \
      pw[0][1][kf] = (u32)bf16bits(p2) | ((u32)bf16bits(p3) << 16);                \
      float4 mv1 = *(const float4*)&mrb1[keyb];                                    \
      p0 = fminf(rintf(__expf(fmaf(s41[0], sscale, mv1.x) - mreg[1]) * cvl[1]), 127.f); \
      p1 = fminf(rintf(__expf(fmaf(s41[1], sscale, mv1.y) - mreg[1]) * cvl[1]), 127.f); \
      p2 = fminf(rintf(__expf(fmaf(s41[2], sscale, mv1.z) - mreg[1]) * cvl[1]), 127.f); \
      p3 = fminf(rintf(__expf(fmaf(s41[3], sscale, mv1.w) - mreg[1]) * cvl[1]), 127.f); \
      pw[1][0][kf] = (u32)bf16bits(p0) | ((u32)bf16bits(p1) << 16);                \
      pw[1][1][kf] = (u32)bf16bits(p2) | ((u32)bf16bits(p3) << 16);                \
    }                                                                              \
    int src0 = ((g & 1) * 2) * 16 + c;                                             \
    int src1 = src0 + 16;                                                          \
    int hi = g >> 1;                                                               \
    bf16x8 pa[2][2];                                                               \
    _Pragma("unroll")                                                              \
    for (int s = 0; s < 2; s++) {                                                  \
      _Pragma("unroll")                                                            \
      for (int u = 0; u < 2; u++) {                                                \
        int a0 = __shfl((int)pw[u][0][2 * s], src0, 64);                           \
        int b0 = __shfl((int)pw[u][0][2 * s + 1], src0, 64);                       \
        int a1 = __shfl((int)pw[u][1][2 * s], src0, 64);                           \
        int b1 = __shfl((int)pw[u][1][2 * s + 1], src0, 64);                       \
        int a2 = __shfl((int)pw[u][0][2 * s], src1, 64);                           \
        int b2 = __shfl((int)pw[u][0][2 * s + 1], src1, 64);                       \
        int a3 = __shfl((int)pw[u][1][2 * s], src1, 64);                           \
        int b3 = __shfl((int)pw[u][1][2 * s + 1], src1, 64);                       \
        int4 wv4;                                                                  \
        wv4.x = hi ? b0 : a0; wv4.y = hi ? b1 : a1;                                \
        wv4.z = hi ? b2 : a2; wv4.w = hi ? b3 : a3;                                \
        pa[u][s] = *(bf16x8*)&wv4;                                                 \
      }                                                                            \
    }                                                                              \
    _Pragma("unroll")                                                              \
    for (int dt = 0; dt < 8; dt++) {                                               \
      int drow = dt * 16 + c;                                                      \
      bf16x8 vf0 = *(const bf16x8*)(Vl[BUF] + drow * 64 + ((g ^ (drow & 7)) * 8)); \
      acc[0][dt] = __builtin_amdgcn_mfma_f32_16x16x32_bf16(pa[0][0], vf0, acc[0][dt], 0, 0, 0); \
      acc[1][dt] = __builtin_amdgcn_mfma_f32_16x16x32_bf16(pa[1][0], vf0, acc[1][dt], 0, 0, 0); \
      bf16x8 vf1 = *(const bf16x8*)(Vl[BUF] + drow * 64 + (((4 + g) ^ (drow & 7)) * 8)); \
      acc[0][dt] = __builtin_amdgcn_mfma_f32_16x16x32_bf16(pa[0][1], vf1, acc[0][dt], 0, 0, 0); \
      acc[1][dt] = __builtin_amdgcn_mfma_f32_16x16x32_bf16(pa[1][1], vf1, acc[1][dt], 0, 0, 0); \
    }                                                                              \
  }

// pass 2: 4 waves x 32 q (128 q/block); swapped QK^T + in-register P; dbuf unroll-2.
// grid = NH*4*KS2 = 512, 256 thr, LDS 64KB -> 2 blocks/CU
__global__ __launch_bounds__(256) void k_mattn2(const u16* __restrict__ QI, const u16* __restrict__ KCb,
                                                const u16* __restrict__ VT, const float* __restrict__ mask,
                                                const float* __restrict__ sc, const float* __restrict__ MLm,
                                                const float* __restrict__ MLl, float* __restrict__ AOp) {
  __shared__ u16 Kl[2][64 * HD];   // 32KB swizzled [key][d]
  __shared__ u16 Vl[2][HD * 64];   // 32KB swizzled [d][key]
  int bid = blockIdx.x;
  int wki = (bid & 7) * (NH * 4 * KS2 / 8) + (bid >> 3);
  int kc = wki >> 6, rem2 = wki & 63, qb = rem2 >> 4, h = rem2 & 15, kv = h >> 2;
  int tid = threadIdx.x, lane = tid & 63, wv = tid >> 6, g = lane >> 4, c = lane & 15;
  float sq  = mk_scale(sc[SC_AMAX_Q]);
  float sck = mk_scale(sc[SC_AMAX_CK]);
  float tqk = fminf(rintf(sc[SC_AMAX_CK_TAIL] / sck), 127.f) * sck;
  float skn = fmaxf(fmaxf(tqk, sc[SC_AMAX_K]), 1e-8f) / 127.f;
  float sscale = sq * skn * INV_SQRT_HD;
  float scv = mk_scale(sc[SC_AMAX_CV]);
  float tqv = fminf(rintf(sc[SC_AMAX_CV_TAIL] / scv), 127.f) * scv;
  float svn = fmaxf(fmaxf(tqv, sc[SC_AMAX_V]), 1e-8f) / 127.f;
  float sp  = mk_scale(1.0f / sc[SC_MIN_L]);
  float rsp = 1.0f / sp;
  float psv = sp * svn;
  int q0 = qb * 128 + wv * 32;
  bf16x8 qf[2][4];
  #pragma unroll
  for (int u = 0; u < 2; u++) {
    const u16* qrow = QI + ((size_t)h * S_LEN + q0 + 16 * u + c) * HD + g * 8;
    #pragma unroll
    for (int ds = 0; ds < 4; ds++) qf[u][ds] = *(const bf16x8*)(qrow + 32 * ds);
  }
  float mreg[2], cvl[2];
  #pragma unroll
  for (int u = 0; u < 2; u++) {
    mreg[u] = MLm[h * S_LEN + q0 + 16 * u + c];
    cvl[u] = rsp / MLl[h * S_LEN + q0 + 16 * u + c];
  }
  const float* mrb0 = mask + (size_t)(q0 + c) * CL;
  const float* mrb1 = mask + (size_t)(q0 + 16 + c) * CL;
  f32x4 acc[2][8] = {};
  const u16* Kg = KCb + (size_t)kv * CL * HD;
  const u16* Vg = VT + (size_t)kv * HD * CL;
  int kbase0 = kc * KCH2;
  M2_STAGE(0, kbase0)
  __syncthreads();
  for (int kb = 0; kb < KCH2; kb += 128) {
    M2_STAGE(1, kbase0 + kb + 64)
    M2_TILE(0, kbase0 + kb)
    __syncthreads();
    if (kb + 128 < KCH2) M2_STAGE(0, kbase0 + kb + 128)
    M2_TILE(1, kbase0 + kb + 64)
    __syncthreads();
  }
  float* outp = AOp + (size_t)kc * S_LEN * HID;
  #pragma unroll
  for (int u = 0; u < 2; u++)
    #pragma unroll
    for (int dt = 0; dt < 8; dt++)
      #pragma unroll
      for (int r = 0; r < 4; r++)
        outp[(size_t)(q0 + 16 * u + 4 * g + r) * HID + h * HD + dt * 16 + c] = acc[u][dt][r] * psv;
}

__global__ __launch_bounds__(256) void k_combine_ao(const float* __restrict__ AOp, float* __restrict__ AO,
                                                    float* __restrict__ PA) {
  int idx = blockIdx.x * 256 + threadIdx.x;   // S*HID/4
  const int st = S_LEN * HID / 4;
  const f32x4* p4 = (const f32x4*)AOp;
  f32x4 a = p4[idx];
  #pragma unroll
  for (int p = 1; p < KS2; p++) {
    f32x4 b = p4[p * st + idx];
    a = a + b;
  }
  *((f32x4*)AO + idx) = a;
  float am = fmaxf(fmaxf(fabsf(a[0]), fabsf(a[1])), fmaxf(fabsf(a[2]), fabsf(a[3])));
  am = blockMax256(am);
  if (threadIdx.x == 0) PA[blockIdx.x] = am;
}

// single block: fold AO partials into SC_AMAX_AO
__global__ __launch_bounds__(256) void k_reduce_ao(const float* __restrict__ PA, float* __restrict__ sc) {
  float v = 0.f;
  #pragma unroll
  for (int i = 0; i < 4; i++) v = fmaxf(v, PA[threadIdx.x + 256 * i]);
  v = blockMax256(v);
  if (threadIdx.x == 0) sc[SC_AMAX_AO] = v;
}

extern "C" void kernel_launch(void* const* d_in, const int* in_sizes, int n_in,
                              void* d_out, int out_size, void* d_ws, size_t ws_size,
                              hipStream_t stream) {
  const float* hidden = (const float*)d_in[0];
  const float* cosb   = (const float*)d_in[1];
  const float* sinb   = (const float*)d_in[2];
  const float* cachek = (const float*)d_in[3];
  const float* cachev = (const float*)d_in[4];
  const float* mask   = (const float*)d_in[5];
  const float* Wq     = (const float*)d_in[6];
  const float* bq     = (const float*)d_in[7];
  const float* Wk     = (const float*)d_in[8];
  const float* bk     = (const float*)d_in[9];
  const float* Wv     = (const float*)d_in[10];
  const float* bv     = (const float*)d_in[11];
  const float* Wo     = (const float*)d_in[12];
  float* out = (float*)d_out;

  char* base = (char*)d_ws;
  auto alloc = [&](size_t bytes) { char* p = base; base += (bytes + 255) & ~(size_t)255; return p; };

  float* SC  = (float*)alloc(64 * 4);
  float* PP  = (float*)alloc(2560 * 4);
  float* PR  = (float*)alloc(2816 * 4);
  float* PA  = (float*)alloc(1024 * 4);
  float* SWq = (float*)alloc(HID * 4);
  float* SWk = (float*)alloc(NKV * HD * 4);
  float* SWv = (float*)alloc(NKV * HD * 4);
  float* SWo = (float*)alloc(HID * 4);
  u16* XI    = (u16*)alloc((size_t)S_LEN * HID * 2);
  u16* WQb   = (u16*)alloc((size_t)HID * HID * 2);
  u16* WKb   = (u16*)alloc((size_t)NKV * HD * HID * 2);
  u16* WVb   = (u16*)alloc((size_t)NKV * HD * HID * 2);
  u16* WOb   = (u16*)alloc((size_t)HID * HID * 2);
  float* QB  = (float*)alloc((size_t)S_LEN * HID * 4);
  float* KB  = (float*)alloc((size_t)S_LEN * NKV * HD * 4);
  float* VB  = (float*)alloc((size_t)S_LEN * NKV * HD * 4);
  u16* KCb   = (u16*)alloc((size_t)NKV * CL * HD * 2);
  u16* VCb   = (u16*)alloc((size_t)NKV * CL * HD * 2);
  u16* VT    = (u16*)alloc((size_t)NKV * HD * CL * 2);
  u16* QI    = (u16*)alloc((size_t)NH * S_LEN * HD * 2);
  float* PM  = (float*)alloc((size_t)KS1 * NH * S_LEN * 4);
  float* PL  = (float*)alloc((size_t)KS1 * NH * S_LEN * 4);
  float* MLm = (float*)alloc((size_t)NH * S_LEN * 4);
  float* MLl = (float*)alloc((size_t)NH * S_LEN * 4);
  float* AOp = (float*)alloc((size_t)KS2 * S_LEN * HID * 4);
  float* AO  = (float*)alloc((size_t)S_LEN * HID * 4);
  u16* AOi   = (u16*)alloc((size_t)S_LEN * HID * 2);

  k_pre<<<1536, 256, 0, stream>>>(hidden, cachek, cachev, PP);
  k_reduce_pre<<<1, 256, 0, stream>>>(PP, SC);
  k_quant_w_all<<<5120, 256, 0, stream>>>(Wq, Wk, Wv, Wo, WQb, WKb, WVb, WOb, SWq, SWk, SWv, SWo);
  k_quant_act_b<<<1024, 256, 0, stream>>>(hidden, XI, S_LEN * HID / 4, SC, SC_AMAX_X);
  {
    dim3 g(48, S_LEN / 64);
    k_gemm_qkv<<<g, 256, 0, stream>>>(XI, WQb, WKb, WVb, SWq, SWk, SWv, bq, bk, bv, SC, QB, KB, VB);
  }
  k_rope_amax<<<2816, 256, 0, stream>>>(QB, KB, VB, cosb, sinb, PR);
  k_reduce_rope<<<1, 256, 0, stream>>>(PR, SC);
  k_build_cache2<<<NKV * 128 * 2, 256, 0, stream>>>(cachek, cachev, KB, VB, KCb, VCb, VT, out, SC);
  k_quant_q<<<1024, 256, 0, stream>>>(QB, QI, SC);
  k_mattn1<<<NH * 4 * KS1, 256, 0, stream>>>(QI, KCb, mask, SC, PM, PL);
  k_merge4<<<NH * S_LEN / 256, 256, 0, stream>>>(PM, PL, MLm, MLl, SC);
  k_mattn2<<<NH * 4 * KS2, 256, 0, stream>>>(QI, KCb, VT, mask, SC, MLm, MLl, AOp);
  k_combine_ao<<<1024, 256, 0, stream>>>(AOp, AO, PA);
  k_reduce_ao<<<1, 256, 0, stream>>>(PA, SC);
  k_quant_act_b<<<1024, 256, 0, stream>>>(AO, AOi, S_LEN * HID / 4, SC, SC_AMAX_AO);
  {
    dim3 g(HID / 64, S_LEN / 64);
    k_gemm_q<<<g, 256, 0, stream>>>(AOi, WOb, SWo, SC, SC_AMAX_AO, out, S_LEN, HID, HID);
  }
  (void)in_sizes; (void)n_in; (void)out_size; (void)ws_size;
}

// Round 14
// 209.625 us; speedup vs baseline: 1.0418x; 1.0418x over previous
//
#include <hip/hip_runtime.h>
#include <math.h>

#define S_LEN 512
#define HID 2048
#define NH 16
#define NKV 4
#define HD 128
#define CL 8192
#define TAILN (CL - S_LEN)
#define NKO (NKV * S_LEN * HD)
#define KS1 16                 // key partitions pass 1 (64-q blocks)
#define KCH1 (CL / KS1)        // 512
#define KS2 8                  // key partitions pass 2 (128-q blocks)
#define KCH2 (CL / KS2)        // 1024
#define INV_SQRT_HD 0.08838834764831845f

typedef unsigned short u16;
typedef unsigned int u32;
typedef __attribute__((ext_vector_type(8))) unsigned short u16x8;
typedef __attribute__((ext_vector_type(4))) unsigned short u16x4;
typedef __attribute__((ext_vector_type(8))) short bf16x8;
typedef __attribute__((ext_vector_type(4))) float f32x4;

enum {
  SC_AMAX_X = 0, SC_AMAX_CK, SC_AMAX_CK_TAIL, SC_AMAX_CV, SC_AMAX_CV_TAIL,
  SC_AMAX_Q, SC_AMAX_K, SC_AMAX_V, SC_AMAX_AO, SC_MIN_L,
  SC_NUM
};

__device__ __forceinline__ float warpMax64(float v) {
  #pragma unroll
  for (int o = 32; o; o >>= 1) v = fmaxf(v, __shfl_down(v, o, 64));
  return v;
}
__device__ __forceinline__ float warpMin64(float v) {
  #pragma unroll
  for (int o = 32; o; o >>= 1) v = fminf(v, __shfl_down(v, o, 64));
  return v;
}
// requires blockDim.x == 256
__device__ __forceinline__ float blockMax256(float v) {
  __shared__ float sm_[4];
  __syncthreads();
  v = warpMax64(v);
  if ((threadIdx.x & 63) == 0) sm_[threadIdx.x >> 6] = v;
  __syncthreads();
  return fmaxf(fmaxf(sm_[0], sm_[1]), fmaxf(sm_[2], sm_[3]));
}
__device__ __forceinline__ float blockMin256(float v) {
  __shared__ float sn_[4];
  __syncthreads();
  v = warpMin64(v);
  if ((threadIdx.x & 63) == 0) sn_[threadIdx.x >> 6] = v;
  __syncthreads();
  return fminf(fminf(sn_[0], sn_[1]), fminf(sn_[2], sn_[3]));
}
__device__ __forceinline__ void atomicMinPosF(float* a, float v) {
  atomicMin((unsigned int*)a, __float_as_uint(v));
}
__device__ __forceinline__ float clampq(float q) {
  return fminf(fmaxf(q, -128.f), 127.f);
}
__device__ __forceinline__ u16 bf16bits(float f) {
  return (u16)(__float_as_uint(f) >> 16);   // exact for small integers
}
__device__ __forceinline__ float mk_scale(float am) {
  return fmaxf(am, 1e-8f) / 127.f;
}
__device__ __forceinline__ void gl2lds16(const u16* g, u16* l) {
  __builtin_amdgcn_global_load_lds((const __attribute__((address_space(1))) void*)g,
                                   (__attribute__((address_space(3))) void*)l, 16, 0, 0);
}

// fused pre-pass absmax: blocks [0,512) hidden, [512,1024) cache_k, [1024,1536) cache_v
__global__ __launch_bounds__(256) void k_pre(const float* __restrict__ hidden,
                                             const float* __restrict__ ck, const float* __restrict__ cv,
                                             float* __restrict__ pp) {
  int b = blockIdx.x, tid = threadIdx.x;
  if (b < 512) {
    const int n4 = S_LEN * HID / 4;
    float m = 0.f;
    const float4* x4 = (const float4*)hidden;
    for (int i = b * 256 + tid; i < n4; i += 512 * 256) {
      float4 v = x4[i];
      m = fmaxf(m, fmaxf(fmaxf(fabsf(v.x), fabsf(v.y)), fmaxf(fabsf(v.z), fabsf(v.w))));
    }
    m = blockMax256(m);
    if (tid == 0) pp[b] = m;
  } else {
    int isv = b >= 1024;
    int bb = b - (isv ? 1024 : 512);
    const float4* x4 = (const float4*)(isv ? cv : ck);
    const int n4 = NKV * CL * HD / 4;
    float mf = 0.f, mt = 0.f;
    for (int i = bb * 256 + tid; i < n4; i += 512 * 256) {
      float4 v = x4[i];
      float a = fmaxf(fmaxf(fabsf(v.x), fabsf(v.y)), fmaxf(fabsf(v.z), fabsf(v.w)));
      mf = fmaxf(mf, a);
      int t = (i >> 5) & (CL - 1);
      if (t >= S_LEN) mt = fmaxf(mt, a);
    }
    mf = blockMax256(mf);
    mt = blockMax256(mt);
    if (tid == 0) {
      pp[512 + isv * 1024 + bb] = mf;
      pp[1024 + isv * 1024 + bb] = mt;
    }
  }
}

// single block: fold 5 ranges of 512 partials into SC slots; also init SC_MIN_L
__global__ __launch_bounds__(256) void k_reduce_pre(const float* __restrict__ pp, float* __restrict__ sc) {
  const int slots[5] = {SC_AMAX_X, SC_AMAX_CK, SC_AMAX_CK_TAIL, SC_AMAX_CV, SC_AMAX_CV_TAIL};
  if (threadIdx.x == 0) sc[SC_MIN_L] = INFINITY;
  #pragma unroll
  for (int r = 0; r < 5; r++) {
    float v = fmaxf(pp[r * 512 + threadIdx.x], pp[r * 512 + 256 + threadIdx.x]);
    v = blockMax256(v);
    if (threadIdx.x == 0) sc[slots[r]] = v;
  }
}

// all 4 weight matrices, one block per output row; single pass (row cached in registers)
__global__ __launch_bounds__(256) void k_quant_w_all(const float* __restrict__ Wq, const float* __restrict__ Wk,
                                                     const float* __restrict__ Wv, const float* __restrict__ Wo,
                                                     u16* __restrict__ WQb, u16* __restrict__ WKb,
                                                     u16* __restrict__ WVb, u16* __restrict__ WOb,
                                                     float* __restrict__ SWq, float* __restrict__ SWk,
                                                     float* __restrict__ SWv, float* __restrict__ SWo) {
  int r = blockIdx.x;
  const float* W; u16* Wb; float* SW; int row;
  if (r < 2048)      { W = Wq; Wb = WQb; SW = SWq; row = r; }
  else if (r < 2560) { W = Wk; Wb = WKb; SW = SWk; row = r - 2048; }
  else if (r < 3072) { W = Wv; Wb = WVb; SW = SWv; row = r - 2560; }
  else               { W = Wo; Wb = WOb; SW = SWo; row = r - 3072; }
  size_t base = (size_t)row * HID;
  const float4* w4 = (const float4*)(W + base);
  int tid = threadIdx.x;
  float4 va = w4[tid];
  float4 vb = w4[tid + 256];
  float am = fmaxf(fmaxf(fmaxf(fabsf(va.x), fabsf(va.y)), fmaxf(fabsf(va.z), fabsf(va.w))),
                   fmaxf(fmaxf(fabsf(vb.x), fabsf(vb.y)), fmaxf(fabsf(vb.z), fabsf(vb.w))));
  am = blockMax256(am);
  float s = fmaxf(am, 1e-8f) / 127.f;
  if (tid == 0) SW[row] = s;
  u16x4 oa, ob;
  oa[0] = bf16bits(clampq(rintf(va.x / s)));
  oa[1] = bf16bits(clampq(rintf(va.y / s)));
  oa[2] = bf16bits(clampq(rintf(va.z / s)));
  oa[3] = bf16bits(clampq(rintf(va.w / s)));
  ob[0] = bf16bits(clampq(rintf(vb.x / s)));
  ob[1] = bf16bits(clampq(rintf(vb.y / s)));
  ob[2] = bf16bits(clampq(rintf(vb.z / s)));
  ob[3] = bf16bits(clampq(rintf(vb.w / s)));
  *(u16x4*)(Wb + base + (size_t)tid * 4) = oa;
  *(u16x4*)(Wb + base + (size_t)(tid + 256) * 4) = ob;
}

// activation fake-quant -> bf16 integer codes; scale computed inline from amax slot
__global__ __launch_bounds__(256) void k_quant_act_b(const float* __restrict__ in, u16* __restrict__ outp,
                                                     int n4, const float* __restrict__ sc, int axslot) {
  float s = mk_scale(sc[axslot]);
  const float4* i4 = (const float4*)in;
  for (int i = blockIdx.x * 256 + threadIdx.x; i < n4; i += gridDim.x * 256) {
    float4 v = i4[i];
    u16x4 o;
    o[0] = bf16bits(clampq(rintf(v.x / s)));
    o[1] = bf16bits(clampq(rintf(v.y / s)));
    o[2] = bf16bits(clampq(rintf(v.z / s)));
    o[3] = bf16bits(clampq(rintf(v.w / s)));
    *(u16x4*)(outp + (size_t)i * 4) = o;
  }
}

// QB f32 [S][NH*HD] -> QI bf16-int [NH][S][HD]
__global__ __launch_bounds__(256) void k_quant_q(const float* __restrict__ QB, u16* __restrict__ QI,
                                                 const float* __restrict__ sc) {
  int idx = blockIdx.x * 256 + threadIdx.x;
  float s = mk_scale(sc[SC_AMAX_Q]);
  int e = idx * 4;
  int srow = e >> 11, rem = e & 2047;
  int h = rem >> 7, d = rem & 127;
  float4 v = *(const float4*)&QB[e];
  u16x4 o;
  o[0] = bf16bits(clampq(rintf(v.x / s)));
  o[1] = bf16bits(clampq(rintf(v.y / s)));
  o[2] = bf16bits(clampq(rintf(v.z / s)));
  o[3] = bf16bits(clampq(rintf(v.w / s)));
  *(u16x4*)(QI + ((size_t)h * S_LEN + srow) * HD + d) = o;
}

#define GQ_STAGE(BUF, K0)                                                          \
  {                                                                                \
    _Pragma("unroll")                                                              \
    for (int i = 0; i < 2; i++) {                                                  \
      int b = tid + i * 256;                                                       \
      int row = b >> 3, c8d = b & 7, c8s = c8d ^ (row & 7);                        \
      gl2lds16(A + (size_t)(r0 + row) * HID + (K0) + c8s * 8, Al[BUF] + b * 8);    \
    }                                                                              \
    _Pragma("unroll")                                                              \
    for (int i = 0; i < 2; i++) {                                                  \
      int b = tid + i * 256;                                                       \
      int row = b >> 3, c8d = b & 7, c8s = c8d ^ (row & 7);                        \
      gl2lds16(B + (size_t)(c0 + row) * HID + (K0) + c8s * 8, Bl[BUF] + b * 8);    \
    }                                                                              \
  }

#define GQ_TILE(BUF)                                                               \
  {                                                                                \
    _Pragma("unroll")                                                              \
    for (int ks = 0; ks < 2; ks++) {                                               \
      bf16x8 af[2], bfr[2];                                                        \
      _Pragma("unroll")                                                            \
      for (int a = 0; a < 2; a++) {                                                \
        int row = wy * 32 + a * 16 + c;                                            \
        af[a] = *(const bf16x8*)(Al[BUF] + row * 64 + (((4 * ks + g) ^ (row & 7)) * 8)); \
      }                                                                            \
      _Pragma("unroll")                                                            \
      for (int b2 = 0; b2 < 2; b2++) {                                             \
        int row = wx * 32 + b2 * 16 + c;                                           \
        bfr[b2] = *(const bf16x8*)(Bl[BUF] + row * 64 + (((4 * ks + g) ^ (row & 7)) * 8)); \
      }                                                                            \
      _Pragma("unroll")                                                            \
      for (int a = 0; a < 2; a++)                                                  \
        _Pragma("unroll")                                                          \
        for (int b2 = 0; b2 < 2; b2++)                                             \
          acc[a][b2] = __builtin_amdgcn_mfma_f32_16x16x32_bf16(af[a], bfr[b2], acc[a][b2], 0, 0, 0); \
    }                                                                              \
  }

// fused QKV GEMM: C = (XI x W^T) * (sx*SW[col]) + bias; 64x64 tiles, dbuf, grid (48, 8)
__global__ __launch_bounds__(256) void k_gemm_qkv(const u16* __restrict__ A,
                                                  const u16* __restrict__ WQb, const u16* __restrict__ WKb,
                                                  const u16* __restrict__ WVb,
                                                  const float* __restrict__ SWq, const float* __restrict__ SWk,
                                                  const float* __restrict__ SWv,
                                                  const float* __restrict__ bq, const float* __restrict__ bk,
                                                  const float* __restrict__ bv,
                                                  const float* __restrict__ sc,
                                                  float* __restrict__ QB, float* __restrict__ KB,
                                                  float* __restrict__ VB) {
  __shared__ u16 Al[2][64 * 64];
  __shared__ u16 Bl[2][64 * 64];
  int bx = blockIdx.x;
  const u16* B; const float* SW; const float* bias; float* C; int N, c0;
  if (bx < 32)      { B = WQb; SW = SWq; bias = bq; C = QB; N = HID; c0 = bx * 64; }
  else if (bx < 40) { B = WKb; SW = SWk; bias = bk; C = KB; N = NKV * HD; c0 = (bx - 32) * 64; }
  else              { B = WVb; SW = SWv; bias = bv; C = VB; N = NKV * HD; c0 = (bx - 40) * 64; }
  int tid = threadIdx.x, lane = tid & 63, w = tid >> 6;
  int g = lane >> 4, c = lane & 15;
  int wy = w >> 1, wx = w & 1;
  int r0 = blockIdx.y * 64;
  float sx = mk_scale(sc[SC_AMAX_X]);
  f32x4 acc[2][2] = {};
  GQ_STAGE(0, 0)
  __syncthreads();
  for (int k0 = 0; k0 < HID; k0 += 128) {
    GQ_STAGE(1, k0 + 64)
    GQ_TILE(0)
    __syncthreads();
    if (k0 + 128 < HID) GQ_STAGE(0, k0 + 128)
    GQ_TILE(1)
    __syncthreads();
  }
  #pragma unroll
  for (int a = 0; a < 2; a++)
    #pragma unroll
    for (int b2 = 0; b2 < 2; b2++) {
      int col = c0 + wx * 32 + b2 * 16 + c;
      float sca = sx * SW[col];
      float bs = bias[col];
      #pragma unroll
      for (int r = 0; r < 4; r++) {
        int row = r0 + wy * 32 + a * 16 + 4 * g + r;
        C[(size_t)row * N + col] = acc[a][b2][r] * sca + bs;
      }
    }
}

// O-projection GEMM (M=S, N=K=HID), dbuf
__global__ __launch_bounds__(256) void k_gemm_q(const u16* __restrict__ A, const u16* __restrict__ B,
                                                const float* __restrict__ SW, const float* __restrict__ sc,
                                                int axslot, float* __restrict__ C, int M, int N, int K) {
  __shared__ u16 Al[2][64 * 64];
  __shared__ u16 Bl[2][64 * 64];
  int tid = threadIdx.x, lane = tid & 63, w = tid >> 6;
  int g = lane >> 4, c = lane & 15;
  int wy = w >> 1, wx = w & 1;
  int r0 = blockIdx.y * 64, c0 = blockIdx.x * 64;
  float sx = mk_scale(sc[axslot]);
  f32x4 acc[2][2] = {};
  GQ_STAGE(0, 0)
  __syncthreads();
  for (int k0 = 0; k0 < HID; k0 += 128) {
    GQ_STAGE(1, k0 + 64)
    GQ_TILE(0)
    __syncthreads();
    if (k0 + 128 < HID) GQ_STAGE(0, k0 + 128)
    GQ_TILE(1)
    __syncthreads();
  }
  #pragma unroll
  for (int a = 0; a < 2; a++)
    #pragma unroll
    for (int b2 = 0; b2 < 2; b2++) {
      int col = c0 + wx * 32 + b2 * 16 + c;
      float sca = sx * SW[col];
      #pragma unroll
      for (int r = 0; r < 4; r++) {
        int row = r0 + wy * 32 + a * 16 + 4 * g + r;
        C[(size_t)row * N + col] = acc[a][b2][r] * sca;
      }
    }
}

// fused: RoPE(Q), RoPE(K), absmax(V) -> per-block partials PR[bid]. grid = 2816
__global__ __launch_bounds__(256) void k_rope_amax(float* __restrict__ QB, float* __restrict__ KB,
                                                   const float* __restrict__ VB,
                                                   const float* __restrict__ cosb, const float* __restrict__ sinb,
                                                   float* __restrict__ PR) {
  const int nQ = S_LEN * NH * 64;     // 524288
  const int nK = S_LEN * NKV * 64;    // 131072
  int idx = blockIdx.x * 256 + threadIdx.x;
  float am = 0.f;
  if (idx < nQ) {
    int s = idx >> 10, rem = idx & 1023, h = rem >> 6, d = rem & 63;
    float c1 = cosb[s * HD + d], s1 = sinb[s * HD + d];
    float c2 = cosb[s * HD + d + 64], s2 = sinb[s * HD + d + 64];
    float* p = &QB[(size_t)s * (NH * HD) + h * HD + d];
    float x1 = p[0], x2 = p[64];
    float y1 = x1 * c1 - x2 * s1;
    float y2 = x2 * c2 + x1 * s2;
    p[0] = y1; p[64] = y2;
    am = fmaxf(fabsf(y1), fabsf(y2));
  } else if (idx < nQ + nK) {
    int j = idx - nQ;
    int s = j >> 8, rem = j & 255, h = rem >> 6, d = rem & 63;
    float c1 = cosb[s * HD + d], s1 = sinb[s * HD + d];
    float c2 = cosb[s * HD + d + 64], s2 = sinb[s * HD + d + 64];
    float* p = &KB[(size_t)s * (NKV * HD) + h * HD + d];
    float x1 = p[0], x2 = p[64];
    float y1 = x1 * c1 - x2 * s1;
    float y2 = x2 * c2 + x1 * s2;
    p[0] = y1; p[64] = y2;
    am = fmaxf(fabsf(y1), fabsf(y2));
  } else {
    int j = idx - nQ - nK;
    float4 v = ((const float4*)VB)[j];
    am = fmaxf(fmaxf(fabsf(v.x), fabsf(v.y)), fmaxf(fabsf(v.z), fabsf(v.w)));
  }
  am = blockMax256(am);
  if (threadIdx.x == 0) PR[blockIdx.x] = am;
}

// single block: fold rope partials into SC_AMAX_{Q,K,V}
__global__ __launch_bounds__(256) void k_reduce_rope(const float* __restrict__ PR, float* __restrict__ sc) {
  float v = 0.f;
  #pragma unroll
  for (int i = 0; i < 8; i++) v = fmaxf(v, PR[threadIdx.x + 256 * i]);
  v = blockMax256(v);
  if (threadIdx.x == 0) sc[SC_AMAX_Q] = v;
  v = fmaxf(PR[2048 + threadIdx.x], PR[2048 + 256 + threadIdx.x]);
  v = blockMax256(v);
  if (threadIdx.x == 0) sc[SC_AMAX_K] = v;
  v = PR[2560 + threadIdx.x];
  v = blockMax256(v);
  if (threadIdx.x == 0) sc[SC_AMAX_V] = v;
}

// fused cache rebuild + V transpose + kvout. grid = NKV*128*2 (K tiles then V tiles)
__global__ __launch_bounds__(256) void k_build_cache2(const float* __restrict__ ck, const float* __restrict__ cv,
                                                      const float* __restrict__ KB, const float* __restrict__ VB,
                                                      u16* __restrict__ KCb, u16* __restrict__ VCb,
                                                      u16* __restrict__ VT, float* __restrict__ dout,
                                                      const float* __restrict__ sc) {
  __shared__ u16 T[64][140];
  int b = blockIdx.x;
  int isv = b >= NKV * 128;
  int bb = b - isv * NKV * 128;
  int kvh = bb >> 7, tb = bb & 127;
  float s1 = mk_scale(sc[isv ? SC_AMAX_CV : SC_AMAX_CK]);
  float tq = fminf(rintf(sc[isv ? SC_AMAX_CV_TAIL : SC_AMAX_CK_TAIL] / s1), 127.f) * s1;
  float s2 = fmaxf(fmaxf(tq, sc[isv ? SC_AMAX_V : SC_AMAX_K]), 1e-8f) / 127.f;
  float so = mk_scale(sc[isv ? SC_AMAX_V : SC_AMAX_K]);
  const float* cache = isv ? cv : ck;
  const float* fresh = isv ? VB : KB;
  u16* Cb = isv ? VCb : KCb;
  int tid = threadIdx.x;
  int t0 = tb * 64;
  #pragma unroll
  for (int i = 0; i < 8; i++) {
    int idx = tid + i * 256;
    int t = idx >> 5, d4 = (idx & 31) << 2;
    int tt = t0 + t;
    float4 x;
    float q0_, q1_, q2_, q3_;
    if (tt < TAILN) {
      x = *(const float4*)&cache[((size_t)kvh * CL + tt + S_LEN) * HD + d4];
      q0_ = clampq(rintf(clampq(rintf(x.x / s1)) * s1 / s2));
      q1_ = clampq(rintf(clampq(rintf(x.y / s1)) * s1 / s2));
      q2_ = clampq(rintf(clampq(rintf(x.z / s1)) * s1 / s2));
      q3_ = clampq(rintf(clampq(rintf(x.w / s1)) * s1 / s2));
    } else {
      x = *(const float4*)&fresh[(size_t)(tt - TAILN) * (NKV * HD) + kvh * HD + d4];
      q0_ = clampq(rintf(x.x / s2));
      q1_ = clampq(rintf(x.y / s2));
      q2_ = clampq(rintf(x.z / s2));
      q3_ = clampq(rintf(x.w / s2));
      float4 o;
      o.x = clampq(rintf(x.x / so)) * so;
      o.y = clampq(rintf(x.y / so)) * so;
      o.z = clampq(rintf(x.z / so)) * so;
      o.w = clampq(rintf(x.w / so)) * so;
      *(float4*)&dout[(size_t)S_LEN * HID + (size_t)isv * NKO +
                      ((size_t)kvh * S_LEN + (tt - TAILN)) * HD + d4] = o;
    }
    u16x4 ov;
    ov[0] = bf16bits(q0_); ov[1] = bf16bits(q1_); ov[2] = bf16bits(q2_); ov[3] = bf16bits(q3_);
    *(u16x4*)(Cb + ((size_t)kvh * CL + tt) * HD + d4) = ov;
    if (isv) *(u16x4*)&T[t][d4] = ov;
  }
  if (isv) {
    __syncthreads();
    #pragma unroll
    for (int i = 0; i < 4; i++) {
      int j = tid + i * 256;          // 0..1023
      int d = j >> 3, tc = (j & 7) << 3;
      u16x8 v;
      #pragma unroll
      for (int k = 0; k < 8; k++) v[k] = T[tc + k][d];
      *(u16x8*)(VT + ((size_t)kvh * HD + d) * CL + t0 + tc) = v;
    }
  }
}

#define M1_STAGE(BUF, KBASE)                                                       \
  {                                                                                \
    const u16* kgt = Kg + (size_t)(KBASE) * HD;                                    \
    _Pragma("unroll")                                                              \
    for (int i = 0; i < 4; i++) {                                                  \
      int b = tid + i * 256;                                                       \
      int row = b >> 4, c8d = b & 15, c8s = c8d ^ (row & 7);                       \
      gl2lds16(kgt + row * HD + c8s * 8, Kl[BUF] + b * 8);                         \
    }                                                                              \
  }

#define M1_TILE(BUF, KBASE)                                                        \
  {                                                                                \
    const int kbase_ = (KBASE);                                                    \
    f32x4 sc4[4];                                                                  \
    _Pragma("unroll")                                                              \
    for (int kf = 0; kf < 4; kf++) {                                               \
      f32x4 s4 = {0.f, 0.f, 0.f, 0.f};                                             \
      int krow = kf * 16 + c;                                                      \
      _Pragma("unroll")                                                            \
      for (int ds = 0; ds < 4; ds++) {                                             \
        bf16x8 kf8 = *(const bf16x8*)(Kl[BUF] + krow * HD + (((4 * ds + g) ^ (krow & 7)) * 8)); \
        s4 = __builtin_amdgcn_mfma_f32_16x16x32_bf16(qf[ds], kf8, s4, 0, 0, 0);    \
      }                                                                            \
      sc4[kf] = s4;                                                                \
    }                                                                              \
    _Pragma("unroll")                                                              \
    for (int r = 0; r < 4; r++) {                                                  \
      float v0 = fmaf(sc4[0][r], sscale, mrb[r * CL + kbase_ + c]);                \
      float v1 = fmaf(sc4[1][r], sscale, mrb[r * CL + kbase_ + 16 + c]);           \
      float v2 = fmaf(sc4[2][r], sscale, mrb[r * CL + kbase_ + 32 + c]);           \
      float v3 = fmaf(sc4[3][r], sscale, mrb[r * CL + kbase_ + 48 + c]);           \
      float tmax = fmaxf(fmaxf(v0, v1), fmaxf(v2, v3));                            \
      float nm = fmaxf(m[r], tmax);                                                \
      float e0 = __expf(v0 - nm), e1 = __expf(v1 - nm);                            \
      float e2 = __expf(v2 - nm), e3 = __expf(v3 - nm);                            \
      float f = __expf(m[r] - nm);                                                 \
      l[r] = fmaf(l[r], f, (e0 + e1) + (e2 + e3));                                 \
      m[r] = nm;                                                                   \
    }                                                                              \
  }

// pass 1: MFMA QK^T, dbuf (unroll-2, compile-time buffers). grid = NH*8*KS1, XCD-chunked
__global__ __launch_bounds__(256) void k_mattn1(const u16* __restrict__ QI, const u16* __restrict__ KCb,
                                                const float* __restrict__ mask, const float* __restrict__ sc,
                                                float* __restrict__ PM, float* __restrict__ PL) {
  __shared__ u16 Kl[2][64 * HD];   // 32 KB
  int bid = blockIdx.x;
  int wki = (bid & 7) * (NH * 8 * KS1 / 8) + (bid >> 3);
  int kc = wki >> 7, rem2 = wki & 127, qb = rem2 >> 4, h = rem2 & 15, kv = h >> 2;
  int tid = threadIdx.x, lane = tid & 63, wv = tid >> 6, g = lane >> 4, c = lane & 15;
  float sq  = mk_scale(sc[SC_AMAX_Q]);
  float sck = mk_scale(sc[SC_AMAX_CK]);
  float tqk = fminf(rintf(sc[SC_AMAX_CK_TAIL] / sck), 127.f) * sck;
  float skn = fmaxf(fmaxf(tqk, sc[SC_AMAX_K]), 1e-8f) / 127.f;
  float sscale = sq * skn * INV_SQRT_HD;
  int q0 = qb * 64 + wv * 16;
  bf16x8 qf[4];
  {
    const u16* qrow = QI + ((size_t)h * S_LEN + q0 + c) * HD + g * 8;
    #pragma unroll
    for (int ds = 0; ds < 4; ds++) qf[ds] = *(const bf16x8*)(qrow + 32 * ds);
  }
  float m[4], l[4];
  #pragma unroll
  for (int r = 0; r < 4; r++) { m[r] = -INFINITY; l[r] = 0.f; }
  int qlane = q0 + 4 * g;
  int kbase0 = kc * KCH1;
  const u16* Kg = KCb + (size_t)kv * CL * HD;
  const float* mrb = mask + (size_t)qlane * CL;
  M1_STAGE(0, kbase0)
  __syncthreads();
  for (int kb = 0; kb < KCH1; kb += 128) {
    M1_STAGE(1, kbase0 + kb + 64)
    M1_TILE(0, kbase0 + kb)
    __syncthreads();
    if (kb + 128 < KCH1) M1_STAGE(0, kbase0 + kb + 128)
    M1_TILE(1, kbase0 + kb + 64)
    __syncthreads();
  }
  #pragma unroll
  for (int r = 0; r < 4; r++) {
    #pragma unroll
    for (int off = 1; off < 16; off <<= 1) {
      float om = __shfl_xor(m[r], off, 64);
      float ol = __shfl_xor(l[r], off, 64);
      float nm = fmaxf(m[r], om);
      l[r] = l[r] * __expf(m[r] - nm) + ol * __expf(om - nm);
      m[r] = nm;
    }
  }
  if (c == 0) {
    size_t base = ((size_t)kc * NH + h) * S_LEN + qlane;
    #pragma unroll
    for (int r = 0; r < 4; r++) { PM[base + r] = m[r]; PL[base + r] = l[r]; }
  }
}

__global__ __launch_bounds__(256) void k_merge4(const float* __restrict__ PM, const float* __restrict__ PL,
                                                float* __restrict__ MLm, float* __restrict__ MLl, float* sc) {
  int idx = blockIdx.x * 256 + threadIdx.x;   // NH*S_LEN = 8192
  const int st = NH * S_LEN;
  float m = PM[idx];
  #pragma unroll
  for (int p = 1; p < KS1; p++) m = fmaxf(m, PM[p * st + idx]);
  float l = 0.f;
  #pragma unroll
  for (int p = 0; p < KS1; p++) l += PL[p * st + idx] * __expf(PM[p * st + idx] - m);
  MLm[idx] = m; MLl[idx] = l;
  float lm = blockMin256(l);
  if (threadIdx.x == 0) atomicMinPosF(&sc[SC_MIN_L], lm);
}

#define M2_STAGE(BUF, KBASE)                                                       \
  {                                                                                \
    const u16* kgt = Kg + (size_t)(KBASE) * HD;                                    \
    const u16* vgt = Vg + (KBASE);                                                 \
    _Pragma("unroll")                                                              \
    for (int i = 0; i < 4; i++) {                                                  \
      int b = tid + i * 256;                                                       \
      int row = b >> 4, c8d = b & 15, c8s = c8d ^ (row & 7);                       \
      gl2lds16(kgt + row * HD + c8s * 8, Kl[BUF] + b * 8);                         \
    }                                                                              \
    _Pragma("unroll")                                                              \
    for (int i = 0; i < 4; i++) {                                                  \
      int b = tid + i * 256;                                                       \
      int row = b >> 3, c8d = b & 7, c8s = c8d ^ (row & 7);                        \
      gl2lds16(vgt + (size_t)row * CL + c8s * 8, Vl[BUF] + b * 8);                 \
    }                                                                              \
  }

// swapped QK^T (integer-exact => bit-identical scores); P assembled in-register via shfl
#define M2_TILE(BUF, KBASE)                                                        \
  {                                                                                \
    const int kbase_ = (KBASE);                                                    \
    u32 pw[2][2][4];  /* [u][word][kf], all compile-time indexed */                \
    _Pragma("unroll")                                                              \
    for (int kf = 0; kf < 4; kf++) {                                               \
      f32x4 s40 = {0.f, 0.f, 0.f, 0.f}, s41 = {0.f, 0.f, 0.f, 0.f};                \
      int krow = kf * 16 + c;                                                      \
      _Pragma("unroll")                                                            \
      for (int ds = 0; ds < 4; ds++) {                                             \
        bf16x8 kf8 = *(const bf16x8*)(Kl[BUF] + krow * HD + (((4 * ds + g) ^ (krow & 7)) * 8)); \
        s40 = __builtin_amdgcn_mfma_f32_16x16x32_bf16(kf8, qf[0][ds], s40, 0, 0, 0); \
        s41 = __builtin_amdgcn_mfma_f32_16x16x32_bf16(kf8, qf[1][ds], s41, 0, 0, 0); \
      }                                                                            \
      int keyb = kbase_ + kf * 16 + 4 * g;                                         \
      float4 mv0 = *(const float4*)&mrb0[keyb];                                    \
      float p0 = fminf(rintf(__expf(fmaf(s40[0], sscale, mv0.x) - mreg[0]) * cvl[0]), 127.f); \
      float p1 = fminf(rintf(__expf(fmaf(s40[1], sscale, mv0.y) - mreg[0]) * cvl[0]), 127.f); \
      float p2 = fminf(rintf(__expf(fmaf(s40[2], sscale, mv0.z) - mreg[0]) * cvl[0]), 127.f); \
      float p3 = fminf(rintf(__expf(fmaf(s40[3], sscale, mv0.w) - mreg[0]) * cvl[0]), 127.f); \
      pw[0][0][kf] = (u32)bf16bits(p0) | ((u32)bf16bits(p1) << 16);                \
      pw[0][1][kf] = (u32)bf16bits(p2) | ((u32)bf16bits(p3) << 16);                \
      float4 mv1 = *(const float4*)&mrb1[keyb];                                    \
      p0 = fminf(rintf(__expf(fmaf(s41[0], sscale, mv1.x) - mreg[1]) * cvl[1]), 127.f); \
      p1 = fminf(rintf(__expf(fmaf(s41[1], sscale, mv1.y) - mreg[1]) * cvl[1]), 127.f); \
      p2 = fminf(rintf(__expf(fmaf(s41[2], sscale, mv1.z) - mreg[1]) * cvl[1]), 127.f); \
      p3 = fminf(rintf(__expf(fmaf(s41[3], sscale, mv1.w) - mreg[1]) * cvl[1]), 127.f); \
      pw[1][0][kf] = (u32)bf16bits(p0) | ((u32)bf16bits(p1) << 16);                \
      pw[1][1][kf] = (u32)bf16bits(p2) | ((u32)bf16bits(p3) << 16);                \
    }                                                                              \
    int src0 = ((g & 1) * 2) * 16 + c;                                             \
    int src1 = src0 + 16;                                                          \
    int hi = g >> 1;                                                               \
    bf16x8 pa[2][2];                                                               \
    _Pragma("unroll")                                                              \
    for (int s = 0; s < 2; s++) {                                                  \
      _Pragma("unroll")                                                            \
      for (int u = 0; u < 2; u++) {                                                \
        int a0 = __shfl((int)pw[u][0][2 * s], src0, 64);                           \
        int b0 = __shfl((int)pw[u][0][2 * s + 1], src0, 64);                       \
        int a1 = __shfl((int)pw[u][1][2 * s], src0, 64);                           \
        int b1 = __shfl((int)pw[u][1][2 * s + 1], src0, 64);                       \
        int a2 = __shfl((int)pw[u][0][2 * s], src1, 64);                           \
        int b2 = __shfl((int)pw[u][0][2 * s + 1], src1, 64);                       \
        int a3 = __shfl((int)pw[u][1][2 * s], src1, 64);                           \
        int b3 = __shfl((int)pw[u][1][2 * s + 1], src1, 64);                       \
        int4 wv4;                                                                  \
        wv4.x = hi ? b0 : a0; wv4.y = hi ? b1 : a1;                                \
        wv4.z = hi ? b2 : a2; wv4.w = hi ? b3 : a3;                                \
        pa[u][s] = *(bf16x8*)&wv4;                                                 \
      }                                                                            \
    }                                                                              \
    _Pragma("unroll")                                                              \
    for (int dt = 0; dt < 8; dt++) {                                               \
      int drow = dt * 16 + c;                                                      \
      bf16x8 vf0 = *(const bf16x8*)(Vl[BUF] + drow * 64 + ((g ^ (drow & 7)) * 8)); \
      acc[0][dt] = __builtin_amdgcn_mfma_f32_16x16x32_bf16(pa[0][0], vf0, acc[0][dt], 0, 0, 0); \
      acc[1][dt] = __builtin_amdgcn_mfma_f32_16x16x32_bf16(pa[1][0], vf0, acc[1][dt], 0, 0, 0); \
      bf16x8 vf1 = *(const bf16x8*)(Vl[BUF] + drow * 64 + (((4 + g) ^ (drow & 7)) * 8)); \
      acc[0][dt] = __builtin_amdgcn_mfma_f32_16x16x32_bf16(pa[0][1], vf1, acc[0][dt], 0, 0, 0); \
      acc[1][dt] = __builtin_amdgcn_mfma_f32_16x16x32_bf16(pa[1][1], vf1, acc[1][dt], 0, 0, 0); \
    }                                                                              \
  }

// pass 2: 4 waves x 32 q (128 q/block); swapped QK^T + in-register P; dbuf unroll-2.
// grid = NH*4*KS2 = 512, 256 thr, LDS 64KB -> 2 blocks/CU
__global__ __launch_bounds__(256) void k_mattn2(const u16* __restrict__ QI, const u16* __restrict__ KCb,
                                                const u16* __restrict__ VT, const float* __restrict__ mask,
                                                const float* __restrict__ sc, const float* __restrict__ MLm,
                                                const float* __restrict__ MLl, float* __restrict__ AOp) {
  __shared__ u16 Kl[2][64 * HD];   // 32KB swizzled [key][d]
  __shared__ u16 Vl[2][HD * 64];   // 32KB swizzled [d][key]
  int bid = blockIdx.x;
  int wki = (bid & 7) * (NH * 4 * KS2 / 8) + (bid >> 3);
  int kc = wki >> 6, rem2 = wki & 63, qb = rem2 >> 4, h = rem2 & 15, kv = h >> 2;
  int tid = threadIdx.x, lane = tid & 63, wv = tid >> 6, g = lane >> 4, c = lane & 15;
  float sq  = mk_scale(sc[SC_AMAX_Q]);
  float sck = mk_scale(sc[SC_AMAX_CK]);
  float tqk = fminf(rintf(sc[SC_AMAX_CK_TAIL] / sck), 127.f) * sck;
  float skn = fmaxf(fmaxf(tqk, sc[SC_AMAX_K]), 1e-8f) / 127.f;
  float sscale = sq * skn * INV_SQRT_HD;
  float scv = mk_scale(sc[SC_AMAX_CV]);
  float tqv = fminf(rintf(sc[SC_AMAX_CV_TAIL] / scv), 127.f) * scv;
  float svn = fmaxf(fmaxf(tqv, sc[SC_AMAX_V]), 1e-8f) / 127.f;
  float sp  = mk_scale(1.0f / sc[SC_MIN_L]);
  float rsp = 1.0f / sp;
  float psv = sp * svn;
  int q0 = qb * 128 + wv * 32;
  bf16x8 qf[2][4];
  #pragma unroll
  for (int u = 0; u < 2; u++) {
    const u16* qrow = QI + ((size_t)h * S_LEN + q0 + 16 * u + c) * HD + g * 8;
    #pragma unroll
    for (int ds = 0; ds < 4; ds++) qf[u][ds] = *(const bf16x8*)(qrow + 32 * ds);
  }
  float mreg[2], cvl[2];
  #pragma unroll
  for (int u = 0; u < 2; u++) {
    mreg[u] = MLm[h * S_LEN + q0 + 16 * u + c];
    cvl[u] = rsp / MLl[h * S_LEN + q0 + 16 * u + c];
  }
  const float* mrb0 = mask + (size_t)(q0 + c) * CL;
  const float* mrb1 = mask + (size_t)(q0 + 16 + c) * CL;
  f32x4 acc[2][8] = {};
  const u16* Kg = KCb + (size_t)kv * CL * HD;
  const u16* Vg = VT + (size_t)kv * HD * CL;
  int kbase0 = kc * KCH2;
  M2_STAGE(0, kbase0)
  __syncthreads();
  for (int kb = 0; kb < KCH2; kb += 128) {
    M2_STAGE(1, kbase0 + kb + 64)
    M2_TILE(0, kbase0 + kb)
    __syncthreads();
    if (kb + 128 < KCH2) M2_STAGE(0, kbase0 + kb + 128)
    M2_TILE(1, kbase0 + kb + 64)
    __syncthreads();
  }
  float* outp = AOp + (size_t)kc * S_LEN * HID;
  #pragma unroll
  for (int u = 0; u < 2; u++)
    #pragma unroll
    for (int dt = 0; dt < 8; dt++)
      #pragma unroll
      for (int r = 0; r < 4; r++)
        outp[(size_t)(q0 + 16 * u + 4 * g + r) * HID + h * HD + dt * 16 + c] = acc[u][dt][r] * psv;
}

__global__ __launch_bounds__(256) void k_combine_ao(const float* __restrict__ AOp, float* __restrict__ AO,
                                                    float* __restrict__ PA) {
  int idx = blockIdx.x * 256 + threadIdx.x;   // S*HID/4
  const int st = S_LEN * HID / 4;
  const f32x4* p4 = (const f32x4*)AOp;
  f32x4 a = p4[idx];
  #pragma unroll
  for (int p = 1; p < KS2; p++) {
    f32x4 b = p4[p * st + idx];
    a = a + b;
  }
  *((f32x4*)AO + idx) = a;
  float am = fmaxf(fmaxf(fabsf(a[0]), fabsf(a[1])), fmaxf(fabsf(a[2]), fabsf(a[3])));
  am = blockMax256(am);
  if (threadIdx.x == 0) PA[blockIdx.x] = am;
}

// single block: fold AO partials into SC_AMAX_AO
__global__ __launch_bounds__(256) void k_reduce_ao(const float* __restrict__ PA, float* __restrict__ sc) {
  float v = 0.f;
  #pragma unroll
  for (int i = 0; i < 4; i++) v = fmaxf(v, PA[threadIdx.x + 256 * i]);
  v = blockMax256(v);
  if (threadIdx.x == 0) sc[SC_AMAX_AO] = v;
}

extern "C" void kernel_launch(void* const* d_in, const int* in_sizes, int n_in,
                              void* d_out, int out_size, void* d_ws, size_t ws_size,
                              hipStream_t stream) {
  const float* hidden = (const float*)d_in[0];
  const float* cosb   = (const float*)d_in[1];
  const float* sinb   = (const float*)d_in[2];
  const float* cachek = (const float*)d_in[3];
  const float* cachev = (const float*)d_in[4];
  const float* mask   = (const float*)d_in[5];
  const float* Wq     = (const float*)d_in[6];
  const float* bq     = (const float*)d_in[7];
  const float* Wk     = (const float*)d_in[8];
  const float* bk     = (const float*)d_in[9];
  const float* Wv     = (const float*)d_in[10];
  const float* bv     = (const float*)d_in[11];
  const float* Wo     = (const float*)d_in[12];
  float* out = (float*)d_out;

  char* base = (char*)d_ws;
  auto alloc = [&](size_t bytes) { char* p = base; base += (bytes + 255) & ~(size_t)255; return p; };

  float* SC  = (float*)alloc(64 * 4);
  float* PP  = (float*)alloc(2560 * 4);
  float* PR  = (float*)alloc(2816 * 4);
  float* PA  = (float*)alloc(1024 * 4);
  float* SWq = (float*)alloc(HID * 4);
  float* SWk = (float*)alloc(NKV * HD * 4);
  float* SWv = (float*)alloc(NKV * HD * 4);
  float* SWo = (float*)alloc(HID * 4);
  u16* XI    = (u16*)alloc((size_t)S_LEN * HID * 2);
  u16* WQb   = (u16*)alloc((size_t)HID * HID * 2);
  u16* WKb   = (u16*)alloc((size_t)NKV * HD * HID * 2);
  u16* WVb   = (u16*)alloc((size_t)NKV * HD * HID * 2);
  u16* WOb   = (u16*)alloc((size_t)HID * HID * 2);
  float* QB  = (float*)alloc((size_t)S_LEN * HID * 4);
  float* KB  = (float*)alloc((size_t)S_LEN * NKV * HD * 4);
  float* VB  = (float*)alloc((size_t)S_LEN * NKV * HD * 4);
  u16* KCb   = (u16*)alloc((size_t)NKV * CL * HD * 2);
  u16* VCb   = (u16*)alloc((size_t)NKV * CL * HD * 2);
  u16* VT    = (u16*)alloc((size_t)NKV * HD * CL * 2);
  u16* QI    = (u16*)alloc((size_t)NH * S_LEN * HD * 2);
  float* PM  = (float*)alloc((size_t)KS1 * NH * S_LEN * 4);
  float* PL  = (float*)alloc((size_t)KS1 * NH * S_LEN * 4);
  float* MLm = (float*)alloc((size_t)NH * S_LEN * 4);
  float* MLl = (float*)alloc((size_t)NH * S_LEN * 4);
  float* AOp = (float*)alloc((size_t)KS2 * S_LEN * HID * 4);
  float* AO  = (float*)alloc((size_t)S_LEN * HID * 4);
  u16* AOi   = (u16*)alloc((size_t)S_LEN * HID * 2);

  k_pre<<<1536, 256, 0, stream>>>(hidden, cachek, cachev, PP);
  k_reduce_pre<<<1, 256, 0, stream>>>(PP, SC);
  k_quant_w_all<<<5120, 256, 0, stream>>>(Wq, Wk, Wv, Wo, WQb, WKb, WVb, WOb, SWq, SWk, SWv, SWo);
  k_quant_act_b<<<1024, 256, 0, stream>>>(hidden, XI, S_LEN * HID / 4, SC, SC_AMAX_X);
  {
    dim3 g(48, S_LEN / 64);
    k_gemm_qkv<<<g, 256, 0, stream>>>(XI, WQb, WKb, WVb, SWq, SWk, SWv, bq, bk, bv, SC, QB, KB, VB);
  }
  k_rope_amax<<<2816, 256, 0, stream>>>(QB, KB, VB, cosb, sinb, PR);
  k_reduce_rope<<<1, 256, 0, stream>>>(PR, SC);
  k_build_cache2<<<NKV * 128 * 2, 256, 0, stream>>>(cachek, cachev, KB, VB, KCb, VCb, VT, out, SC);
  k_quant_q<<<1024, 256, 0, stream>>>(QB, QI, SC);
  k_mattn1<<<NH * 8 * KS1, 256, 0, stream>>>(QI, KCb, mask, SC, PM, PL);
  k_merge4<<<NH * S_LEN / 256, 256, 0, stream>>>(PM, PL, MLm, MLl, SC);
  k_mattn2<<<NH * 4 * KS2, 256, 0, stream>>>(QI, KCb, VT, mask, SC, MLm, MLl, AOp);
  k_combine_ao<<<1024, 256, 0, stream>>>(AOp, AO, PA);
  k_reduce_ao<<<1, 256, 0, stream>>>(PA, SC);
  k_quant_act_b<<<1024, 256, 0, stream>>>(AO, AOi, S_LEN * HID / 4, SC, SC_AMAX_AO);
  {
    dim3 g(HID / 64, S_LEN / 64);
    k_gemm_q<<<g, 256, 0, stream>>>(AOi, WOb, SWo, SC, SC_AMAX_AO, out, S_LEN, HID, HID);
  }
  (void)in_sizes; (void)n_in; (void)out_size; (void)ws_size;
}

// Round 15
// 208.551 us; speedup vs baseline: 1.0471x; 1.0051x over previous
//
#include <hip/hip_runtime.h>
#include <math.h>

#define S_LEN 512
#define HID 2048
#define NH 16
#define NKV 4
#define HD 128
#define CL 8192
#define TAILN (CL - S_LEN)
#define NKO (NKV * S_LEN * HD)
#define KS1 16                 // key partitions pass 1 (16-q x 4-head blocks)
#define KCH1 (CL / KS1)        // 512
#define KS2 8                  // key partitions pass 2 (32-q x 4-head blocks)
#define KCH2 (CL / KS2)        // 1024
#define INV_SQRT_HD 0.08838834764831845f

typedef unsigned short u16;
typedef unsigned int u32;
typedef __attribute__((ext_vector_type(8))) unsigned short u16x8;
typedef __attribute__((ext_vector_type(4))) unsigned short u16x4;
typedef __attribute__((ext_vector_type(8))) short bf16x8;
typedef __attribute__((ext_vector_type(4))) float f32x4;

enum {
  SC_AMAX_X = 0, SC_AMAX_CK, SC_AMAX_CK_TAIL, SC_AMAX_CV, SC_AMAX_CV_TAIL,
  SC_AMAX_Q, SC_AMAX_K, SC_AMAX_V, SC_AMAX_AO, SC_MIN_L,
  SC_NUM
};

__device__ __forceinline__ float warpMax64(float v) {
  #pragma unroll
  for (int o = 32; o; o >>= 1) v = fmaxf(v, __shfl_down(v, o, 64));
  return v;
}
__device__ __forceinline__ float warpMin64(float v) {
  #pragma unroll
  for (int o = 32; o; o >>= 1) v = fminf(v, __shfl_down(v, o, 64));
  return v;
}
// requires blockDim.x == 256
__device__ __forceinline__ float blockMax256(float v) {
  __shared__ float sm_[4];
  __syncthreads();
  v = warpMax64(v);
  if ((threadIdx.x & 63) == 0) sm_[threadIdx.x >> 6] = v;
  __syncthreads();
  return fmaxf(fmaxf(sm_[0], sm_[1]), fmaxf(sm_[2], sm_[3]));
}
__device__ __forceinline__ float blockMin256(float v) {
  __shared__ float sn_[4];
  __syncthreads();
  v = warpMin64(v);
  if ((threadIdx.x & 63) == 0) sn_[threadIdx.x >> 6] = v;
  __syncthreads();
  return fminf(fminf(sn_[0], sn_[1]), fminf(sn_[2], sn_[3]));
}
__device__ __forceinline__ void atomicMinPosF(float* a, float v) {
  atomicMin((unsigned int*)a, __float_as_uint(v));
}
__device__ __forceinline__ float clampq(float q) {
  return fminf(fmaxf(q, -128.f), 127.f);
}
__device__ __forceinline__ u16 bf16bits(float f) {
  return (u16)(__float_as_uint(f) >> 16);   // exact for small integers
}
__device__ __forceinline__ float mk_scale(float am) {
  return fmaxf(am, 1e-8f) / 127.f;
}
__device__ __forceinline__ void gl2lds16(const u16* g, u16* l) {
  __builtin_amdgcn_global_load_lds((const __attribute__((address_space(1))) void*)g,
                                   (__attribute__((address_space(3))) void*)l, 16, 0, 0);
}

// fused pre-pass absmax: blocks [0,512) hidden, [512,1024) cache_k, [1024,1536) cache_v
__global__ __launch_bounds__(256) void k_pre(const float* __restrict__ hidden,
                                             const float* __restrict__ ck, const float* __restrict__ cv,
                                             float* __restrict__ pp) {
  int b = blockIdx.x, tid = threadIdx.x;
  if (b < 512) {
    const int n4 = S_LEN * HID / 4;
    float m = 0.f;
    const float4* x4 = (const float4*)hidden;
    for (int i = b * 256 + tid; i < n4; i += 512 * 256) {
      float4 v = x4[i];
      m = fmaxf(m, fmaxf(fmaxf(fabsf(v.x), fabsf(v.y)), fmaxf(fabsf(v.z), fabsf(v.w))));
    }
    m = blockMax256(m);
    if (tid == 0) pp[b] = m;
  } else {
    int isv = b >= 1024;
    int bb = b - (isv ? 1024 : 512);
    const float4* x4 = (const float4*)(isv ? cv : ck);
    const int n4 = NKV * CL * HD / 4;
    float mf = 0.f, mt = 0.f;
    for (int i = bb * 256 + tid; i < n4; i += 512 * 256) {
      float4 v = x4[i];
      float a = fmaxf(fmaxf(fabsf(v.x), fabsf(v.y)), fmaxf(fabsf(v.z), fabsf(v.w)));
      mf = fmaxf(mf, a);
      int t = (i >> 5) & (CL - 1);
      if (t >= S_LEN) mt = fmaxf(mt, a);
    }
    mf = blockMax256(mf);
    mt = blockMax256(mt);
    if (tid == 0) {
      pp[512 + isv * 1024 + bb] = mf;
      pp[1024 + isv * 1024 + bb] = mt;
    }
  }
}

// single block: fold 5 ranges of 512 partials into SC slots; also init SC_MIN_L
__global__ __launch_bounds__(256) void k_reduce_pre(const float* __restrict__ pp, float* __restrict__ sc) {
  const int slots[5] = {SC_AMAX_X, SC_AMAX_CK, SC_AMAX_CK_TAIL, SC_AMAX_CV, SC_AMAX_CV_TAIL};
  if (threadIdx.x == 0) sc[SC_MIN_L] = INFINITY;
  #pragma unroll
  for (int r = 0; r < 5; r++) {
    float v = fmaxf(pp[r * 512 + threadIdx.x], pp[r * 512 + 256 + threadIdx.x]);
    v = blockMax256(v);
    if (threadIdx.x == 0) sc[slots[r]] = v;
  }
}

// all 4 weight matrices, one block per output row; single pass (row cached in registers)
__global__ __launch_bounds__(256) void k_quant_w_all(const float* __restrict__ Wq, const float* __restrict__ Wk,
                                                     const float* __restrict__ Wv, const float* __restrict__ Wo,
                                                     u16* __restrict__ WQb, u16* __restrict__ WKb,
                                                     u16* __restrict__ WVb, u16* __restrict__ WOb,
                                                     float* __restrict__ SWq, float* __restrict__ SWk,
                                                     float* __restrict__ SWv, float* __restrict__ SWo) {
  int r = blockIdx.x;
  const float* W; u16* Wb; float* SW; int row;
  if (r < 2048)      { W = Wq; Wb = WQb; SW = SWq; row = r; }
  else if (r < 2560) { W = Wk; Wb = WKb; SW = SWk; row = r - 2048; }
  else if (r < 3072) { W = Wv; Wb = WVb; SW = SWv; row = r - 2560; }
  else               { W = Wo; Wb = WOb; SW = SWo; row = r - 3072; }
  size_t base = (size_t)row * HID;
  const float4* w4 = (const float4*)(W + base);
  int tid = threadIdx.x;
  float4 va = w4[tid];
  float4 vb = w4[tid + 256];
  float am = fmaxf(fmaxf(fmaxf(fabsf(va.x), fabsf(va.y)), fmaxf(fabsf(va.z), fabsf(va.w))),
                   fmaxf(fmaxf(fabsf(vb.x), fabsf(vb.y)), fmaxf(fabsf(vb.z), fabsf(vb.w))));
  am = blockMax256(am);
  float s = fmaxf(am, 1e-8f) / 127.f;
  if (tid == 0) SW[row] = s;
  u16x4 oa, ob;
  oa[0] = bf16bits(clampq(rintf(va.x / s)));
  oa[1] = bf16bits(clampq(rintf(va.y / s)));
  oa[2] = bf16bits(clampq(rintf(va.z / s)));
  oa[3] = bf16bits(clampq(rintf(va.w / s)));
  ob[0] = bf16bits(clampq(rintf(vb.x / s)));
  ob[1] = bf16bits(clampq(rintf(vb.y / s)));
  ob[2] = bf16bits(clampq(rintf(vb.z / s)));
  ob[3] = bf16bits(clampq(rintf(vb.w / s)));
  *(u16x4*)(Wb + base + (size_t)tid * 4) = oa;
  *(u16x4*)(Wb + base + (size_t)(tid + 256) * 4) = ob;
}

// activation fake-quant -> bf16 integer codes; scale computed inline from amax slot
__global__ __launch_bounds__(256) void k_quant_act_b(const float* __restrict__ in, u16* __restrict__ outp,
                                                     int n4, const float* __restrict__ sc, int axslot) {
  float s = mk_scale(sc[axslot]);
  const float4* i4 = (const float4*)in;
  for (int i = blockIdx.x * 256 + threadIdx.x; i < n4; i += gridDim.x * 256) {
    float4 v = i4[i];
    u16x4 o;
    o[0] = bf16bits(clampq(rintf(v.x / s)));
    o[1] = bf16bits(clampq(rintf(v.y / s)));
    o[2] = bf16bits(clampq(rintf(v.z / s)));
    o[3] = bf16bits(clampq(rintf(v.w / s)));
    *(u16x4*)(outp + (size_t)i * 4) = o;
  }
}

// QB f32 [S][NH*HD] -> QI bf16-int [NH][S][HD]
__global__ __launch_bounds__(256) void k_quant_q(const float* __restrict__ QB, u16* __restrict__ QI,
                                                 const float* __restrict__ sc) {
  int idx = blockIdx.x * 256 + threadIdx.x;
  float s = mk_scale(sc[SC_AMAX_Q]);
  int e = idx * 4;
  int srow = e >> 11, rem = e & 2047;
  int h = rem >> 7, d = rem & 127;
  float4 v = *(const float4*)&QB[e];
  u16x4 o;
  o[0] = bf16bits(clampq(rintf(v.x / s)));
  o[1] = bf16bits(clampq(rintf(v.y / s)));
  o[2] = bf16bits(clampq(rintf(v.z / s)));
  o[3] = bf16bits(clampq(rintf(v.w / s)));
  *(u16x4*)(QI + ((size_t)h * S_LEN + srow) * HD + d) = o;
}

#define GQ_STAGE(BUF, K0)                                                          \
  {                                                                                \
    _Pragma("unroll")                                                              \
    for (int i = 0; i < 2; i++) {                                                  \
      int b = tid + i * 256;                                                       \
      int row = b >> 3, c8d = b & 7, c8s = c8d ^ (row & 7);                        \
      gl2lds16(A + (size_t)(r0 + row) * HID + (K0) + c8s * 8, Al[BUF] + b * 8);    \
    }                                                                              \
    _Pragma("unroll")                                                              \
    for (int i = 0; i < 2; i++) {                                                  \
      int b = tid + i * 256;                                                       \
      int row = b >> 3, c8d = b & 7, c8s = c8d ^ (row & 7);                        \
      gl2lds16(B + (size_t)(c0 + row) * HID + (K0) + c8s * 8, Bl[BUF] + b * 8);    \
    }                                                                              \
  }

#define GQ_TILE(BUF)                                                               \
  {                                                                                \
    _Pragma("unroll")                                                              \
    for (int ks = 0; ks < 2; ks++) {                                               \
      bf16x8 af[2], bfr[2];                                                        \
      _Pragma("unroll")                                                            \
      for (int a = 0; a < 2; a++) {                                                \
        int row = wy * 32 + a * 16 + c;                                            \
        af[a] = *(const bf16x8*)(Al[BUF] + row * 64 + (((4 * ks + g) ^ (row & 7)) * 8)); \
      }                                                                            \
      _Pragma("unroll")                                                            \
      for (int b2 = 0; b2 < 2; b2++) {                                             \
        int row = wx * 32 + b2 * 16 + c;                                           \
        bfr[b2] = *(const bf16x8*)(Bl[BUF] + row * 64 + (((4 * ks + g) ^ (row & 7)) * 8)); \
      }                                                                            \
      _Pragma("unroll")                                                            \
      for (int a = 0; a < 2; a++)                                                  \
        _Pragma("unroll")                                                          \
        for (int b2 = 0; b2 < 2; b2++)                                             \
          acc[a][b2] = __builtin_amdgcn_mfma_f32_16x16x32_bf16(af[a], bfr[b2], acc[a][b2], 0, 0, 0); \
    }                                                                              \
  }

// fused QKV GEMM: C = (XI x W^T) * (sx*SW[col]) + bias; 64x64 tiles, dbuf, grid (48, 8)
__global__ __launch_bounds__(256) void k_gemm_qkv(const u16* __restrict__ A,
                                                  const u16* __restrict__ WQb, const u16* __restrict__ WKb,
                                                  const u16* __restrict__ WVb,
                                                  const float* __restrict__ SWq, const float* __restrict__ SWk,
                                                  const float* __restrict__ SWv,
                                                  const float* __restrict__ bq, const float* __restrict__ bk,
                                                  const float* __restrict__ bv,
                                                  const float* __restrict__ sc,
                                                  float* __restrict__ QB, float* __restrict__ KB,
                                                  float* __restrict__ VB) {
  __shared__ u16 Al[2][64 * 64];
  __shared__ u16 Bl[2][64 * 64];
  int bx = blockIdx.x;
  const u16* B; const float* SW; const float* bias; float* C; int N, c0;
  if (bx < 32)      { B = WQb; SW = SWq; bias = bq; C = QB; N = HID; c0 = bx * 64; }
  else if (bx < 40) { B = WKb; SW = SWk; bias = bk; C = KB; N = NKV * HD; c0 = (bx - 32) * 64; }
  else              { B = WVb; SW = SWv; bias = bv; C = VB; N = NKV * HD; c0 = (bx - 40) * 64; }
  int tid = threadIdx.x, lane = tid & 63, w = tid >> 6;
  int g = lane >> 4, c = lane & 15;
  int wy = w >> 1, wx = w & 1;
  int r0 = blockIdx.y * 64;
  float sx = mk_scale(sc[SC_AMAX_X]);
  f32x4 acc[2][2] = {};
  GQ_STAGE(0, 0)
  __syncthreads();
  for (int k0 = 0; k0 < HID; k0 += 128) {
    GQ_STAGE(1, k0 + 64)
    GQ_TILE(0)
    __syncthreads();
    if (k0 + 128 < HID) GQ_STAGE(0, k0 + 128)
    GQ_TILE(1)
    __syncthreads();
  }
  #pragma unroll
  for (int a = 0; a < 2; a++)
    #pragma unroll
    for (int b2 = 0; b2 < 2; b2++) {
      int col = c0 + wx * 32 + b2 * 16 + c;
      float sca = sx * SW[col];
      float bs = bias[col];
      #pragma unroll
      for (int r = 0; r < 4; r++) {
        int row = r0 + wy * 32 + a * 16 + 4 * g + r;
        C[(size_t)row * N + col] = acc[a][b2][r] * sca + bs;
      }
    }
}

// O-projection GEMM (M=S, N=K=HID), dbuf
__global__ __launch_bounds__(256) void k_gemm_q(const u16* __restrict__ A, const u16* __restrict__ B,
                                                const float* __restrict__ SW, const float* __restrict__ sc,
                                                int axslot, float* __restrict__ C, int M, int N, int K) {
  __shared__ u16 Al[2][64 * 64];
  __shared__ u16 Bl[2][64 * 64];
  int tid = threadIdx.x, lane = tid & 63, w = tid >> 6;
  int g = lane >> 4, c = lane & 15;
  int wy = w >> 1, wx = w & 1;
  int r0 = blockIdx.y * 64, c0 = blockIdx.x * 64;
  float sx = mk_scale(sc[axslot]);
  f32x4 acc[2][2] = {};
  GQ_STAGE(0, 0)
  __syncthreads();
  for (int k0 = 0; k0 < HID; k0 += 128) {
    GQ_STAGE(1, k0 + 64)
    GQ_TILE(0)
    __syncthreads();
    if (k0 + 128 < HID) GQ_STAGE(0, k0 + 128)
    GQ_TILE(1)
    __syncthreads();
  }
  #pragma unroll
  for (int a = 0; a < 2; a++)
    #pragma unroll
    for (int b2 = 0; b2 < 2; b2++) {
      int col = c0 + wx * 32 + b2 * 16 + c;
      float sca = sx * SW[col];
      #pragma unroll
      for (int r = 0; r < 4; r++) {
        int row = r0 + wy * 32 + a * 16 + 4 * g + r;
        C[(size_t)row * N + col] = acc[a][b2][r] * sca;
      }
    }
}

// fused: RoPE(Q), RoPE(K), absmax(V) -> per-block partials PR[bid]. grid = 2816
__global__ __launch_bounds__(256) void k_rope_amax(float* __restrict__ QB, float* __restrict__ KB,
                                                   const float* __restrict__ VB,
                                                   const float* __restrict__ cosb, const float* __restrict__ sinb,
                                                   float* __restrict__ PR) {
  const int nQ = S_LEN * NH * 64;     // 524288
  const int nK = S_LEN * NKV * 64;    // 131072
  int idx = blockIdx.x * 256 + threadIdx.x;
  float am = 0.f;
  if (idx < nQ) {
    int s = idx >> 10, rem = idx & 1023, h = rem >> 6, d = rem & 63;
    float c1 = cosb[s * HD + d], s1 = sinb[s * HD + d];
    float c2 = cosb[s * HD + d + 64], s2 = sinb[s * HD + d + 64];
    float* p = &QB[(size_t)s * (NH * HD) + h * HD + d];
    float x1 = p[0], x2 = p[64];
    float y1 = x1 * c1 - x2 * s1;
    float y2 = x2 * c2 + x1 * s2;
    p[0] = y1; p[64] = y2;
    am = fmaxf(fabsf(y1), fabsf(y2));
  } else if (idx < nQ + nK) {
    int j = idx - nQ;
    int s = j >> 8, rem = j & 255, h = rem >> 6, d = rem & 63;
    float c1 = cosb[s * HD + d], s1 = sinb[s * HD + d];
    float c2 = cosb[s * HD + d + 64], s2 = sinb[s * HD + d + 64];
    float* p = &KB[(size_t)s * (NKV * HD) + h * HD + d];
    float x1 = p[0], x2 = p[64];
    float y1 = x1 * c1 - x2 * s1;
    float y2 = x2 * c2 + x1 * s2;
    p[0] = y1; p[64] = y2;
    am = fmaxf(fabsf(y1), fabsf(y2));
  } else {
    int j = idx - nQ - nK;
    float4 v = ((const float4*)VB)[j];
    am = fmaxf(fmaxf(fabsf(v.x), fabsf(v.y)), fmaxf(fabsf(v.z), fabsf(v.w)));
  }
  am = blockMax256(am);
  if (threadIdx.x == 0) PR[blockIdx.x] = am;
}

// single block: fold rope partials into SC_AMAX_{Q,K,V}
__global__ __launch_bounds__(256) void k_reduce_rope(const float* __restrict__ PR, float* __restrict__ sc) {
  float v = 0.f;
  #pragma unroll
  for (int i = 0; i < 8; i++) v = fmaxf(v, PR[threadIdx.x + 256 * i]);
  v = blockMax256(v);
  if (threadIdx.x == 0) sc[SC_AMAX_Q] = v;
  v = fmaxf(PR[2048 + threadIdx.x], PR[2048 + 256 + threadIdx.x]);
  v = blockMax256(v);
  if (threadIdx.x == 0) sc[SC_AMAX_K] = v;
  v = PR[2560 + threadIdx.x];
  v = blockMax256(v);
  if (threadIdx.x == 0) sc[SC_AMAX_V] = v;
}

// fused cache rebuild + V transpose + kvout. grid = NKV*128*2 (K tiles then V tiles)
// VCb is never consumed downstream (mattn2 reads VT) -> V branch writes only VT.
__global__ __launch_bounds__(256) void k_build_cache2(const float* __restrict__ ck, const float* __restrict__ cv,
                                                      const float* __restrict__ KB, const float* __restrict__ VB,
                                                      u16* __restrict__ KCb, u16* __restrict__ VT,
                                                      float* __restrict__ dout, const float* __restrict__ sc) {
  __shared__ u16 T[64][140];
  int b = blockIdx.x;
  int isv = b >= NKV * 128;
  int bb = b - isv * NKV * 128;
  int kvh = bb >> 7, tb = bb & 127;
  float s1 = mk_scale(sc[isv ? SC_AMAX_CV : SC_AMAX_CK]);
  float tq = fminf(rintf(sc[isv ? SC_AMAX_CV_TAIL : SC_AMAX_CK_TAIL] / s1), 127.f) * s1;
  float s2 = fmaxf(fmaxf(tq, sc[isv ? SC_AMAX_V : SC_AMAX_K]), 1e-8f) / 127.f;
  float so = mk_scale(sc[isv ? SC_AMAX_V : SC_AMAX_K]);
  const float* cache = isv ? cv : ck;
  const float* fresh = isv ? VB : KB;
  int tid = threadIdx.x;
  int t0 = tb * 64;
  #pragma unroll
  for (int i = 0; i < 8; i++) {
    int idx = tid + i * 256;
    int t = idx >> 5, d4 = (idx & 31) << 2;
    int tt = t0 + t;
    float4 x;
    float q0_, q1_, q2_, q3_;
    if (tt < TAILN) {
      x = *(const float4*)&cache[((size_t)kvh * CL + tt + S_LEN) * HD + d4];
      q0_ = clampq(rintf(clampq(rintf(x.x / s1)) * s1 / s2));
      q1_ = clampq(rintf(clampq(rintf(x.y / s1)) * s1 / s2));
      q2_ = clampq(rintf(clampq(rintf(x.z / s1)) * s1 / s2));
      q3_ = clampq(rintf(clampq(rintf(x.w / s1)) * s1 / s2));
    } else {
      x = *(const float4*)&fresh[(size_t)(tt - TAILN) * (NKV * HD) + kvh * HD + d4];
      q0_ = clampq(rintf(x.x / s2));
      q1_ = clampq(rintf(x.y / s2));
      q2_ = clampq(rintf(x.z / s2));
      q3_ = clampq(rintf(x.w / s2));
      float4 o;
      o.x = clampq(rintf(x.x / so)) * so;
      o.y = clampq(rintf(x.y / so)) * so;
      o.z = clampq(rintf(x.z / so)) * so;
      o.w = clampq(rintf(x.w / so)) * so;
      *(float4*)&dout[(size_t)S_LEN * HID + (size_t)isv * NKO +
                      ((size_t)kvh * S_LEN + (tt - TAILN)) * HD + d4] = o;
    }
    u16x4 ov;
    ov[0] = bf16bits(q0_); ov[1] = bf16bits(q1_); ov[2] = bf16bits(q2_); ov[3] = bf16bits(q3_);
    if (isv) *(u16x4*)&T[t][d4] = ov;
    else *(u16x4*)(KCb + ((size_t)kvh * CL + tt) * HD + d4) = ov;
  }
  if (isv) {
    __syncthreads();
    #pragma unroll
    for (int i = 0; i < 4; i++) {
      int j = tid + i * 256;          // 0..1023
      int d = j >> 3, tc = (j & 7) << 3;
      u16x8 v;
      #pragma unroll
      for (int k = 0; k < 8; k++) v[k] = T[tc + k][d];
      *(u16x8*)(VT + ((size_t)kvh * HD + d) * CL + t0 + tc) = v;
    }
  }
}

#define M1_STAGE(BUF, KBASE)                                                       \
  {                                                                                \
    const u16* kgt = Kg + (size_t)(KBASE) * HD;                                    \
    _Pragma("unroll")                                                              \
    for (int i = 0; i < 4; i++) {                                                  \
      int b = tid + i * 256;                                                       \
      int row = b >> 4, c8d = b & 15, c8s = c8d ^ (row & 7);                       \
      gl2lds16(kgt + row * HD + c8s * 8, Kl[BUF] + b * 8);                         \
    }                                                                              \
  }

#define M1_TILE(BUF, KBASE)                                                        \
  {                                                                                \
    const int kbase_ = (KBASE);                                                    \
    f32x4 sc4[4];                                                                  \
    _Pragma("unroll")                                                              \
    for (int kf = 0; kf < 4; kf++) {                                               \
      f32x4 s4 = {0.f, 0.f, 0.f, 0.f};                                             \
      int krow = kf * 16 + c;                                                      \
      _Pragma("unroll")                                                            \
      for (int ds = 0; ds < 4; ds++) {                                             \
        bf16x8 kf8 = *(const bf16x8*)(Kl[BUF] + krow * HD + (((4 * ds + g) ^ (krow & 7)) * 8)); \
        s4 = __builtin_amdgcn_mfma_f32_16x16x32_bf16(qf[ds], kf8, s4, 0, 0, 0);    \
      }                                                                            \
      sc4[kf] = s4;                                                                \
    }                                                                              \
    _Pragma("unroll")                                                              \
    for (int r = 0; r < 4; r++) {                                                  \
      float v0 = fmaf(sc4[0][r], sscale, mrb[r * CL + kbase_ + c]);                \
      float v1 = fmaf(sc4[1][r], sscale, mrb[r * CL + kbase_ + 16 + c]);           \
      float v2 = fmaf(sc4[2][r], sscale, mrb[r * CL + kbase_ + 32 + c]);           \
      float v3 = fmaf(sc4[3][r], sscale, mrb[r * CL + kbase_ + 48 + c]);           \
      float tmax = fmaxf(fmaxf(v0, v1), fmaxf(v2, v3));                            \
      float nm = fmaxf(m[r], tmax);                                                \
      float e0 = __expf(v0 - nm), e1 = __expf(v1 - nm);                            \
      float e2 = __expf(v2 - nm), e3 = __expf(v3 - nm);                            \
      float f = __expf(m[r] - nm);                                                 \
      l[r] = fmaf(l[r], f, (e0 + e1) + (e2 + e3));                                 \
      m[r] = nm;                                                                   \
    }                                                                              \
  }

// pass 1: MFMA QK^T, dbuf. Block = (kv, qb, kc); WAVE = q-head (4 heads share mask rows).
// grid = NKV*32*KS1 = 2048, 256 thr, XCD-chunked
__global__ __launch_bounds__(256) void k_mattn1(const u16* __restrict__ QI, const u16* __restrict__ KCb,
                                                const float* __restrict__ mask, const float* __restrict__ sc,
                                                float* __restrict__ PM, float* __restrict__ PL) {
  __shared__ u16 Kl[2][64 * HD];   // 32 KB
  int bid = blockIdx.x;
  int wki = (bid & 7) * (NKV * 32 * KS1 / 8) + (bid >> 3);
  int kc = wki >> 7, rem2 = wki & 127, kv = rem2 >> 5, qb = rem2 & 31;
  int tid = threadIdx.x, lane = tid & 63, wv = tid >> 6, g = lane >> 4, c = lane & 15;
  int h = kv * 4 + wv;
  float sq  = mk_scale(sc[SC_AMAX_Q]);
  float sck = mk_scale(sc[SC_AMAX_CK]);
  float tqk = fminf(rintf(sc[SC_AMAX_CK_TAIL] / sck), 127.f) * sck;
  float skn = fmaxf(fmaxf(tqk, sc[SC_AMAX_K]), 1e-8f) / 127.f;
  float sscale = sq * skn * INV_SQRT_HD;
  int q0 = qb * 16;
  bf16x8 qf[4];
  {
    const u16* qrow = QI + ((size_t)h * S_LEN + q0 + c) * HD + g * 8;
    #pragma unroll
    for (int ds = 0; ds < 4; ds++) qf[ds] = *(const bf16x8*)(qrow + 32 * ds);
  }
  float m[4], l[4];
  #pragma unroll
  for (int r = 0; r < 4; r++) { m[r] = -INFINITY; l[r] = 0.f; }
  int qlane = q0 + 4 * g;
  int kbase0 = kc * KCH1;
  const u16* Kg = KCb + (size_t)kv * CL * HD;
  const float* mrb = mask + (size_t)qlane * CL;   // head-independent: shared by all 4 waves
  M1_STAGE(0, kbase0)
  __syncthreads();
  for (int kb = 0; kb < KCH1; kb += 128) {
    M1_STAGE(1, kbase0 + kb + 64)
    M1_TILE(0, kbase0 + kb)
    __syncthreads();
    if (kb + 128 < KCH1) M1_STAGE(0, kbase0 + kb + 128)
    M1_TILE(1, kbase0 + kb + 64)
    __syncthreads();
  }
  #pragma unroll
  for (int r = 0; r < 4; r++) {
    #pragma unroll
    for (int off = 1; off < 16; off <<= 1) {
      float om = __shfl_xor(m[r], off, 64);
      float ol = __shfl_xor(l[r], off, 64);
      float nm = fmaxf(m[r], om);
      l[r] = l[r] * __expf(m[r] - nm) + ol * __expf(om - nm);
      m[r] = nm;
    }
  }
  if (c == 0) {
    size_t base = ((size_t)kc * NH + h) * S_LEN + qlane;
    #pragma unroll
    for (int r = 0; r < 4; r++) { PM[base + r] = m[r]; PL[base + r] = l[r]; }
  }
}

__global__ __launch_bounds__(256) void k_merge4(const float* __restrict__ PM, const float* __restrict__ PL,
                                                float* __restrict__ MLm, float* __restrict__ MLl, float* sc) {
  int idx = blockIdx.x * 256 + threadIdx.x;   // NH*S_LEN = 8192
  const int st = NH * S_LEN;
  float m = PM[idx];
  #pragma unroll
  for (int p = 1; p < KS1; p++) m = fmaxf(m, PM[p * st + idx]);
  float l = 0.f;
  #pragma unroll
  for (int p = 0; p < KS1; p++) l += PL[p * st + idx] * __expf(PM[p * st + idx] - m);
  MLm[idx] = m; MLl[idx] = l;
  float lm = blockMin256(l);
  if (threadIdx.x == 0) atomicMinPosF(&sc[SC_MIN_L], lm);
}

#define M2_STAGE(BUF, KBASE)                                                       \
  {                                                                                \
    const u16* kgt = Kg + (size_t)(KBASE) * HD;                                    \
    const u16* vgt = Vg + (KBASE);                                                 \
    _Pragma("unroll")                                                              \
    for (int i = 0; i < 4; i++) {                                                  \
      int b = tid + i * 256;                                                       \
      int row = b >> 4, c8d = b & 15, c8s = c8d ^ (row & 7);                       \
      gl2lds16(kgt + row * HD + c8s * 8, Kl[BUF] + b * 8);                         \
    }                                                                              \
    _Pragma("unroll")                                                              \
    for (int i = 0; i < 4; i++) {                                                  \
      int b = tid + i * 256;                                                       \
      int row = b >> 3, c8d = b & 7, c8s = c8d ^ (row & 7);                        \
      gl2lds16(vgt + (size_t)row * CL + c8s * 8, Vl[BUF] + b * 8);                 \
    }                                                                              \
  }

// swapped QK^T (integer-exact => bit-identical scores); P assembled in-register via shfl
#define M2_TILE(BUF, KBASE)                                                        \
  {                                                                                \
    const int kbase_ = (KBASE);                                                    \
    u32 pw[2][2][4];  /* [u][word][kf], all compile-time indexed */                \
    _Pragma("unroll")                                                              \
    for (int kf = 0; kf < 4; kf++) {                                               \
      f32x4 s40 = {0.f, 0.f, 0.f, 0.f}, s41 = {0.f, 0.f, 0.f, 0.f};                \
      int krow = kf * 16 + c;                                                      \
      _Pragma("unroll")                                                            \
      for (int ds = 0; ds < 4; ds++) {                                             \
        bf16x8 kf8 = *(const bf16x8*)(Kl[BUF] + krow * HD + (((4 * ds + g) ^ (krow & 7)) * 8)); \
        s40 = __builtin_amdgcn_mfma_f32_16x16x32_bf16(kf8, qf[0][ds], s40, 0, 0, 0); \
        s41 = __builtin_amdgcn_mfma_f32_16x16x32_bf16(kf8, qf[1][ds], s41, 0, 0, 0); \
      }                                                                            \
      int keyb = kbase_ + kf * 16 + 4 * g;                                         \
      float4 mv0 = *(const float4*)&mrb0[keyb];                                    \
      float p0 = fminf(rintf(__expf(fmaf(s40[0], sscale, mv0.x) - mreg[0]) * cvl[0]), 127.f); \
      float p1 = fminf(rintf(__expf(fmaf(s40[1], sscale, mv0.y) - mreg[0]) * cvl[0]), 127.f); \
      float p2 = fminf(rintf(__expf(fmaf(s40[2], sscale, mv0.z) - mreg[0]) * cvl[0]), 127.f); \
      float p3 = fminf(rintf(__expf(fmaf(s40[3], sscale, mv0.w) - mreg[0]) * cvl[0]), 127.f); \
      pw[0][0][kf] = (u32)bf16bits(p0) | ((u32)bf16bits(p1) << 16);                \
      pw[0][1][kf] = (u32)bf16bits(p2) | ((u32)bf16bits(p3) << 16);                \
      float4 mv1 = *(const float4*)&mrb1[keyb];                                    \
      p0 = fminf(rintf(__expf(fmaf(s41[0], sscale, mv1.x) - mreg[1]) * cvl[1]), 127.f); \
      p1 = fminf(rintf(__expf(fmaf(s41[1], sscale, mv1.y) - mreg[1]) * cvl[1]), 127.f); \
      p2 = fminf(rintf(__expf(fmaf(s41[2], sscale, mv1.z) - mreg[1]) * cvl[1]), 127.f); \
      p3 = fminf(rintf(__expf(fmaf(s41[3], sscale, mv1.w) - mreg[1]) * cvl[1]), 127.f); \
      pw[1][0][kf] = (u32)bf16bits(p0) | ((u32)bf16bits(p1) << 16);                \
      pw[1][1][kf] = (u32)bf16bits(p2) | ((u32)bf16bits(p3) << 16);                \
    }                                                                              \
    int src0 = ((g & 1) * 2) * 16 + c;                                             \
    int src1 = src0 + 16;                                                          \
    int hi = g >> 1;                                                               \
    bf16x8 pa[2][2];                                                               \
    _Pragma("unroll")                                                              \
    for (int s = 0; s < 2; s++) {                                                  \
      _Pragma("unroll")                                                            \
      for (int u = 0; u < 2; u++) {                                                \
        int a0 = __shfl((int)pw[u][0][2 * s], src0, 64);                           \
        int b0 = __shfl((int)pw[u][0][2 * s + 1], src0, 64);                       \
        int a1 = __shfl((int)pw[u][1][2 * s], src0, 64);                           \
        int b1 = __shfl((int)pw[u][1][2 * s + 1], src0, 64);                       \
        int a2 = __shfl((int)pw[u][0][2 * s], src1, 64);                           \
        int b2 = __shfl((int)pw[u][0][2 * s + 1], src1, 64);                       \
        int a3 = __shfl((int)pw[u][1][2 * s], src1, 64);                           \
        int b3 = __shfl((int)pw[u][1][2 * s + 1], src1, 64);                       \
        int4 wv4;                                                                  \
        wv4.x = hi ? b0 : a0; wv4.y = hi ? b1 : a1;                                \
        wv4.z = hi ? b2 : a2; wv4.w = hi ? b3 : a3;                                \
        pa[u][s] = *(bf16x8*)&wv4;                                                 \
      }                                                                            \
    }                                                                              \
    _Pragma("unroll")                                                              \
    for (int dt = 0; dt < 8; dt++) {                                               \
      int drow = dt * 16 + c;                                                      \
      bf16x8 vf0 = *(const bf16x8*)(Vl[BUF] + drow * 64 + ((g ^ (drow & 7)) * 8)); \
      acc[0][dt] = __builtin_amdgcn_mfma_f32_16x16x32_bf16(pa[0][0], vf0, acc[0][dt], 0, 0, 0); \
      acc[1][dt] = __builtin_amdgcn_mfma_f32_16x16x32_bf16(pa[1][0], vf0, acc[1][dt], 0, 0, 0); \
      bf16x8 vf1 = *(const bf16x8*)(Vl[BUF] + drow * 64 + (((4 + g) ^ (drow & 7)) * 8)); \
      acc[0][dt] = __builtin_amdgcn_mfma_f32_16x16x32_bf16(pa[0][1], vf1, acc[0][dt], 0, 0, 0); \
      acc[1][dt] = __builtin_amdgcn_mfma_f32_16x16x32_bf16(pa[1][1], vf1, acc[1][dt], 0, 0, 0); \
    }                                                                              \
  }

// pass 2: Block = (kv, qb 32q, kc); WAVE = q-head (4 heads share mask rows).
// swapped QK^T + in-register P; dbuf unroll-2. grid = NKV*16*KS2 = 512, 256 thr, LDS 64KB
__global__ __launch_bounds__(256) void k_mattn2(const u16* __restrict__ QI, const u16* __restrict__ KCb,
                                                const u16* __restrict__ VT, const float* __restrict__ mask,
                                                const float* __restrict__ sc, const float* __restrict__ MLm,
                                                const float* __restrict__ MLl, float* __restrict__ AOp) {
  __shared__ u16 Kl[2][64 * HD];   // 32KB swizzled [key][d]
  __shared__ u16 Vl[2][HD * 64];   // 32KB swizzled [d][key]
  int bid = blockIdx.x;
  int wki = (bid & 7) * (NKV * 16 * KS2 / 8) + (bid >> 3);
  int kc = wki >> 6, rem2 = wki & 63, kv = rem2 >> 4, qb = rem2 & 15;
  int tid = threadIdx.x, lane = tid & 63, wv = tid >> 6, g = lane >> 4, c = lane & 15;
  int h = kv * 4 + wv;
  float sq  = mk_scale(sc[SC_AMAX_Q]);
  float sck = mk_scale(sc[SC_AMAX_CK]);
  float tqk = fminf(rintf(sc[SC_AMAX_CK_TAIL] / sck), 127.f) * sck;
  float skn = fmaxf(fmaxf(tqk, sc[SC_AMAX_K]), 1e-8f) / 127.f;
  float sscale = sq * skn * INV_SQRT_HD;
  float scv = mk_scale(sc[SC_AMAX_CV]);
  float tqv = fminf(rintf(sc[SC_AMAX_CV_TAIL] / scv), 127.f) * scv;
  float svn = fmaxf(fmaxf(tqv, sc[SC_AMAX_V]), 1e-8f) / 127.f;
  float sp  = mk_scale(1.0f / sc[SC_MIN_L]);
  float rsp = 1.0f / sp;
  float psv = sp * svn;
  int q0 = qb * 32;
  bf16x8 qf[2][4];
  #pragma unroll
  for (int u = 0; u < 2; u++) {
    const u16* qrow = QI + ((size_t)h * S_LEN + q0 + 16 * u + c) * HD + g * 8;
    #pragma unroll
    for (int ds = 0; ds < 4; ds++) qf[u][ds] = *(const bf16x8*)(qrow + 32 * ds);
  }
  float mreg[2], cvl[2];
  #pragma unroll
  for (int u = 0; u < 2; u++) {
    mreg[u] = MLm[h * S_LEN + q0 + 16 * u + c];
    cvl[u] = rsp / MLl[h * S_LEN + q0 + 16 * u + c];
  }
  const float* mrb0 = mask + (size_t)(q0 + c) * CL;        // head-independent
  const float* mrb1 = mask + (size_t)(q0 + 16 + c) * CL;
  f32x4 acc[2][8] = {};
  const u16* Kg = KCb + (size_t)kv * CL * HD;
  const u16* Vg = VT + (size_t)kv * HD * CL;
  int kbase0 = kc * KCH2;
  M2_STAGE(0, kbase0)
  __syncthreads();
  for (int kb = 0; kb < KCH2; kb += 128) {
    M2_STAGE(1, kbase0 + kb + 64)
    M2_TILE(0, kbase0 + kb)
    __syncthreads();
    if (kb + 128 < KCH2) M2_STAGE(0, kbase0 + kb + 128)
    M2_TILE(1, kbase0 + kb + 64)
    __syncthreads();
  }
  float* outp = AOp + (size_t)kc * S_LEN * HID;
  #pragma unroll
  for (int u = 0; u < 2; u++)
    #pragma unroll
    for (int dt = 0; dt < 8; dt++)
      #pragma unroll
      for (int r = 0; r < 4; r++)
        outp[(size_t)(q0 + 16 * u + 4 * g + r) * HID + h * HD + dt * 16 + c] = acc[u][dt][r] * psv;
}

__global__ __launch_bounds__(256) void k_combine_ao(const float* __restrict__ AOp, float* __restrict__ AO,
                                                    float* __restrict__ PA) {
  int idx = blockIdx.x * 256 + threadIdx.x;   // S*HID/4
  const int st = S_LEN * HID / 4;
  const f32x4* p4 = (const f32x4*)AOp;
  f32x4 a = p4[idx];
  #pragma unroll
  for (int p = 1; p < KS2; p++) {
    f32x4 b = p4[p * st + idx];
    a = a + b;
  }
  *((f32x4*)AO + idx) = a;
  float am = fmaxf(fmaxf(fabsf(a[0]), fabsf(a[1])), fmaxf(fabsf(a[2]), fabsf(a[3])));
  am = blockMax256(am);
  if (threadIdx.x == 0) PA[blockIdx.x] = am;
}

// single block: fold AO partials into SC_AMAX_AO
__global__ __launch_bounds__(256) void k_reduce_ao(const float* __restrict__ PA, float* __restrict__ sc) {
  float v = 0.f;
  #pragma unroll
  for (int i = 0; i < 4; i++) v = fmaxf(v, PA[threadIdx.x + 256 * i]);
  v = blockMax256(v);
  if (threadIdx.x == 0) sc[SC_AMAX_AO] = v;
}

extern "C" void kernel_launch(void* const* d_in, const int* in_sizes, int n_in,
                              void* d_out, int out_size, void* d_ws, size_t ws_size,
                              hipStream_t stream) {
  const float* hidden = (const float*)d_in[0];
  const float* cosb   = (const float*)d_in[1];
  const float* sinb   = (const float*)d_in[2];
  const float* cachek = (const float*)d_in[3];
  const float* cachev = (const float*)d_in[4];
  const float* mask   = (const float*)d_in[5];
  const float* Wq     = (const float*)d_in[6];
  const float* bq     = (const float*)d_in[7];
  const float* Wk     = (const float*)d_in[8];
  const float* bk     = (const float*)d_in[9];
  const float* Wv     = (const float*)d_in[10];
  const float* bv     = (const float*)d_in[11];
  const float* Wo     = (const float*)d_in[12];
  float* out = (float*)d_out;

  char* base = (char*)d_ws;
  auto alloc = [&](size_t bytes) { char* p = base; base += (bytes + 255) & ~(size_t)255; return p; };

  float* SC  = (float*)alloc(64 * 4);
  float* PP  = (float*)alloc(2560 * 4);
  float* PR  = (float*)alloc(2816 * 4);
  float* PA  = (float*)alloc(1024 * 4);
  float* SWq = (float*)alloc(HID * 4);
  float* SWk = (float*)alloc(NKV * HD * 4);
  float* SWv = (float*)alloc(NKV * HD * 4);
  float* SWo = (float*)alloc(HID * 4);
  u16* XI    = (u16*)alloc((size_t)S_LEN * HID * 2);
  u16* WQb   = (u16*)alloc((size_t)HID * HID * 2);
  u16* WKb   = (u16*)alloc((size_t)NKV * HD * HID * 2);
  u16* WVb   = (u16*)alloc((size_t)NKV * HD * HID * 2);
  u16* WOb   = (u16*)alloc((size_t)HID * HID * 2);
  float* QB  = (float*)alloc((size_t)S_LEN * HID * 4);
  float* KB  = (float*)alloc((size_t)S_LEN * NKV * HD * 4);
  float* VB  = (float*)alloc((size_t)S_LEN * NKV * HD * 4);
  u16* KCb   = (u16*)alloc((size_t)NKV * CL * HD * 2);
  u16* VT    = (u16*)alloc((size_t)NKV * HD * CL * 2);
  u16* QI    = (u16*)alloc((size_t)NH * S_LEN * HD * 2);
  float* PM  = (float*)alloc((size_t)KS1 * NH * S_LEN * 4);
  float* PL  = (float*)alloc((size_t)KS1 * NH * S_LEN * 4);
  float* MLm = (float*)alloc((size_t)NH * S_LEN * 4);
  float* MLl = (float*)alloc((size_t)NH * S_LEN * 4);
  float* AOp = (float*)alloc((size_t)KS2 * S_LEN * HID * 4);
  float* AO  = (float*)alloc((size_t)S_LEN * HID * 4);
  u16* AOi   = (u16*)alloc((size_t)S_LEN * HID * 2);

  k_pre<<<1536, 256, 0, stream>>>(hidden, cachek, cachev, PP);
  k_reduce_pre<<<1, 256, 0, stream>>>(PP, SC);
  k_quant_w_all<<<5120, 256, 0, stream>>>(Wq, Wk, Wv, Wo, WQb, WKb, WVb, WOb, SWq, SWk, SWv, SWo);
  k_quant_act_b<<<1024, 256, 0, stream>>>(hidden, XI, S_LEN * HID / 4, SC, SC_AMAX_X);
  {
    dim3 g(48, S_LEN / 64);
    k_gemm_qkv<<<g, 256, 0, stream>>>(XI, WQb, WKb, WVb, SWq, SWk, SWv, bq, bk, bv, SC, QB, KB, VB);
  }
  k_rope_amax<<<2816, 256, 0, stream>>>(QB, KB, VB, cosb, sinb, PR);
  k_reduce_rope<<<1, 256, 0, stream>>>(PR, SC);
  k_build_cache2<<<NKV * 128 * 2, 256, 0, stream>>>(cachek, cachev, KB, VB, KCb, VT, out, SC);
  k_quant_q<<<1024, 256, 0, stream>>>(QB, QI, SC);
  k_mattn1<<<NKV * 32 * KS1, 256, 0, stream>>>(QI, KCb, mask, SC, PM, PL);
  k_merge4<<<NH * S_LEN / 256, 256, 0, stream>>>(PM, PL, MLm, MLl, SC);
  k_mattn2<<<NKV * 16 * KS2, 256, 0, stream>>>(QI, KCb, VT, mask, SC, MLm, MLl, AOp);
  k_combine_ao<<<1024, 256, 0, stream>>>(AOp, AO, PA);
  k_reduce_ao<<<1, 256, 0, stream>>>(PA, SC);
  k_quant_act_b<<<1024, 256, 0, stream>>>(AO, AOi, S_LEN * HID / 4, SC, SC_AMAX_AO);
  {
    dim3 g(HID / 64, S_LEN / 64);
    k_gemm_q<<<g, 256, 0, stream>>>(AOi, WOb, SWo, SC, SC_AMAX_AO, out, S_LEN, HID, HID);
  }
  (void)in_sizes; (void)n_in; (void)out_size; (void)ws_size;
}